// Round 1
// baseline (326.640 us; speedup 1.0000x reference)
//
#include <hip/hip_runtime.h>

#define HWQ  4096      // H*W = 64*64
#define NCAM 6
#define IMH  32
#define IMW  88
#define NPIX (IMH*IMW) // 2816

// ---------------------------------------------------------------------------
// Generic batched SGEMM: C[z] = A @ B[z] + bias, optional relu / transposed C.
// A: [M,K] row-major (shared across batch). B: [K,N] row-major per batch.
// flags: 1 = relu, 2 = store C transposed as C[n*M + m] (pixel-major KV).
// Tiles: BM=BN=64, BK=16, 256 threads, 4x4 microtile per thread.
// ---------------------------------------------------------------------------
__global__ __launch_bounds__(256) void sgemm_kernel(
    const float* __restrict__ A, const float* __restrict__ B,
    const float* __restrict__ bias, float* __restrict__ C,
    int M, int N, int K, int flags,
    long strideB, long strideC)
{
    __shared__ float As[16][68];   // [k][m], +4 pad -> aligned float4, 2-way max
    __shared__ float Bs[16][68];   // [k][n]

    const float* Bb = B + (size_t)blockIdx.z * strideB;
    float*       Cb = C + (size_t)blockIdx.z * strideC;

    const int tid = threadIdx.x;
    const int bm = blockIdx.y * 64, bn = blockIdx.x * 64;
    const int tm = ((tid >> 4) & 15) << 2;   // 0..60
    const int tn = (tid & 15) << 2;          // 0..60

    float acc[4][4] = {{0.f,0.f,0.f,0.f},{0.f,0.f,0.f,0.f},
                       {0.f,0.f,0.f,0.f},{0.f,0.f,0.f,0.f}};

    for (int k0 = 0; k0 < K; k0 += 16) {
        #pragma unroll
        for (int i = 0; i < 4; ++i) {         // A tile: 64m x 16k
            int idx = tid + i * 256;
            int mk = idx >> 4;                // m 0..63
            int kk = idx & 15;
            int gm = bm + mk;
            As[kk][mk] = (gm < M) ? A[(size_t)gm * K + (k0 + kk)] : 0.f;
        }
        #pragma unroll
        for (int i = 0; i < 4; ++i) {         // B tile: 16k x 64n
            int idx = tid + i * 256;
            int kk = idx >> 6;                // 0..15
            int nn = idx & 63;
            Bs[kk][nn] = Bb[(size_t)(k0 + kk) * N + (bn + nn)];
        }
        __syncthreads();
        #pragma unroll
        for (int kk = 0; kk < 16; ++kk) {
            const float4 av = *(const float4*)&As[kk][tm];
            const float4 bv = *(const float4*)&Bs[kk][tn];
            const float a[4]  = {av.x, av.y, av.z, av.w};
            const float bb[4] = {bv.x, bv.y, bv.z, bv.w};
            #pragma unroll
            for (int i = 0; i < 4; ++i)
                #pragma unroll
                for (int j = 0; j < 4; ++j)
                    acc[i][j] += a[i] * bb[j];
        }
        __syncthreads();
    }

    if (flags & 2) {
        // transposed store (used for KV: M=256 full tiles, no guards needed)
        const float b0 = bias[bm+tm+0], b1 = bias[bm+tm+1];
        const float b2 = bias[bm+tm+2], b3 = bias[bm+tm+3];
        #pragma unroll
        for (int j = 0; j < 4; ++j) {
            int gn = bn + tn + j;
            float4 v = make_float4(acc[0][j]+b0, acc[1][j]+b1,
                                   acc[2][j]+b2, acc[3][j]+b3);
            *(float4*)&Cb[(size_t)gn * M + (bm + tm)] = v;
        }
    } else {
        #pragma unroll
        for (int i = 0; i < 4; ++i) {
            int gm = bm + tm + i;
            if (gm >= M) continue;
            float bi = bias[gm];
            float4 v = make_float4(acc[i][0]+bi, acc[i][1]+bi,
                                   acc[i][2]+bi, acc[i][3]+bi);
            if (flags & 1) {
                v.x = fmaxf(v.x, 0.f); v.y = fmaxf(v.y, 0.f);
                v.z = fmaxf(v.z, 0.f); v.w = fmaxf(v.w, 0.f);
            }
            *(float4*)&Cb[(size_t)gm * N + (bn + tn)] = v;
        }
    }
}

// ---------------------------------------------------------------------------
// Camera projection: grid[b][n][hw][2]
// ---------------------------------------------------------------------------
__global__ __launch_bounds__(256) void grid_kernel(
    const float* __restrict__ E, const float* __restrict__ Km,
    const float* __restrict__ wxy, float* __restrict__ gridbuf)
{
    int idx = blockIdx.x * 256 + threadIdx.x;     // 0 .. 2*6*4096-1
    int hw = idx & (HWQ - 1);
    int bn = idx >> 12;                           // b*6+n
    float x = wxy[hw], y = wxy[HWQ + hw];
    const float* e = E + bn * 16;
    const float* k = Km + bn * 9;
    // xyz1 = [x, y, 0, 1]
    float cam0 = e[0]*x + e[1]*y + e[3];
    float cam1 = e[4]*x + e[5]*y + e[7];
    float cam2 = e[8]*x + e[9]*y + e[11];
    float px = k[0]*cam0 + k[1]*cam1 + k[2]*cam2;
    float py = k[3]*cam0 + k[4]*cam1 + k[5]*cam2;
    float pz = k[6]*cam0 + k[7]*cam1 + k[8]*cam2;
    pz = fmaxf(pz, 1e-6f);                        // jnp.clip(pz, 1e-6, None)
    float u = px / pz, v = py / pz;
    float gx = u / (float)(IMW - 1) * 2.f - 1.f;
    float gy = v / (float)(IMH - 1) * 2.f - 1.f;
    gridbuf[(size_t)idx * 2 + 0] = gx;
    gridbuf[(size_t)idx * 2 + 1] = gy;
}

// ---------------------------------------------------------------------------
// Fused deformable sampling + attention.
// Thread = (b, q, m, n) with n padded to 8 lane-slots (6 active).
// KV layout: [b][n][pix][256] (ch 0..127 = K, 128..255 = V), pixel-major so
// each bilinear tap reads 32 contiguous channels (float4s).
// Reduction over n via __shfl_xor within 8-lane groups.
// ---------------------------------------------------------------------------
__global__ __launch_bounds__(256) void attn_kernel(
    const float* __restrict__ kv,      // [b][n][NPIX][256]
    const float* __restrict__ qbuf,    // [b][128][HWQ]
    const float* __restrict__ offbuf,  // [b][16][HWQ]
    const float* __restrict__ gridbuf, // [b][n][HWQ][2]
    float* __restrict__ outw)          // [b][128][HWQ]
{
    const int tid = threadIdx.x;
    const int s  = tid & 7;            // camera slot (0..7, 6 active)
    const int m  = (tid >> 3) & 3;     // head
    const int ql = tid >> 5;           // q within block (0..7)
    const int qg = blockIdx.x * 8 + ql;
    const int b  = qg >> 12;
    const int hw = qg & (HWQ - 1);

    float out[32];
    #pragma unroll
    for (int d = 0; d < 32; ++d) out[d] = 0.f;

    if (s < NCAM) {
        const int n = s;
        float qv[32];
        const float* qrow = qbuf + ((size_t)b * 128 + m * 32) * HWQ + hw;
        #pragma unroll
        for (int d = 0; d < 32; ++d) qv[d] = qrow[(size_t)d * HWQ];

        const float* g = gridbuf + (((size_t)b * NCAM + n) * HWQ + hw) * 2;
        const float gx = g[0], gy = g[1];
        const float* offp  = offbuf + (size_t)b * 16 * HWQ + hw;
        const float* slice = kv + ((size_t)b * NCAM + n) * NPIX * 256 + m * 32;

        float sim[8];
        // ---- pass 1: K sampling + q.k dot -----------------------------
        #pragma unroll
        for (int p = 0; p < 8; ++p) {
            float ox = offp[(size_t)(2*p)   * HWQ];
            float oy = offp[(size_t)(2*p+1) * HWQ];
            float sx = fminf(fmaxf(gx + ox, -1.f), 1.f);
            float sy = fminf(fmaxf(gy + oy, -1.f), 1.f);
            float ixf = (sx + 1.f) * 0.5f * (float)(IMW - 1);
            float iyf = (sy + 1.f) * 0.5f * (float)(IMH - 1);
            float x0f = floorf(ixf), y0f = floorf(iyf);
            float fx = ixf - x0f, fy = iyf - y0f;
            int x0 = (int)x0f, y0 = (int)y0f;
            int x1 = min(x0 + 1, IMW - 1);
            int y1 = min(y0 + 1, IMH - 1);
            float w00 = (1.f-fx)*(1.f-fy), w01 = fx*(1.f-fy);
            float w10 = (1.f-fx)*fy,       w11 = fx*fy;
            const float4* c00 = (const float4*)(slice + (size_t)(y0*IMW + x0) * 256);
            const float4* c01 = (const float4*)(slice + (size_t)(y0*IMW + x1) * 256);
            const float4* c10 = (const float4*)(slice + (size_t)(y1*IMW + x0) * 256);
            const float4* c11 = (const float4*)(slice + (size_t)(y1*IMW + x1) * 256);
            float sdot = 0.f;
            #pragma unroll
            for (int d4 = 0; d4 < 8; ++d4) {
                float4 va = c00[d4], vb = c01[d4], vc = c10[d4], vd = c11[d4];
                float k0 = w00*va.x + w01*vb.x + w10*vc.x + w11*vd.x;
                float k1 = w00*va.y + w01*vb.y + w10*vc.y + w11*vd.y;
                float k2 = w00*va.z + w01*vb.z + w10*vc.z + w11*vd.z;
                float k3 = w00*va.w + w01*vb.w + w10*vc.w + w11*vd.w;
                sdot += qv[4*d4+0]*k0 + qv[4*d4+1]*k1
                      + qv[4*d4+2]*k2 + qv[4*d4+3]*k3;
            }
            sim[p] = sdot;
        }
        // ---- softmax over p ------------------------------------------
        float mx = sim[0];
        #pragma unroll
        for (int p = 1; p < 8; ++p) mx = fmaxf(mx, sim[p]);
        float ssum = 0.f;
        #pragma unroll
        for (int p = 0; p < 8; ++p) { sim[p] = __expf(sim[p] - mx); ssum += sim[p]; }

        // ---- pass 2: V sampling, weighted accumulate -----------------
        #pragma unroll
        for (int p = 0; p < 8; ++p) {
            float ox = offp[(size_t)(2*p)   * HWQ];
            float oy = offp[(size_t)(2*p+1) * HWQ];
            float sx = fminf(fmaxf(gx + ox, -1.f), 1.f);
            float sy = fminf(fmaxf(gy + oy, -1.f), 1.f);
            float ixf = (sx + 1.f) * 0.5f * (float)(IMW - 1);
            float iyf = (sy + 1.f) * 0.5f * (float)(IMH - 1);
            float x0f = floorf(ixf), y0f = floorf(iyf);
            float fx = ixf - x0f, fy = iyf - y0f;
            int x0 = (int)x0f, y0 = (int)y0f;
            int x1 = min(x0 + 1, IMW - 1);
            int y1 = min(y0 + 1, IMH - 1);
            float w00 = (1.f-fx)*(1.f-fy), w01 = fx*(1.f-fy);
            float w10 = (1.f-fx)*fy,       w11 = fx*fy;
            const float4* c00 = (const float4*)(slice + 128 + (size_t)(y0*IMW + x0) * 256);
            const float4* c01 = (const float4*)(slice + 128 + (size_t)(y0*IMW + x1) * 256);
            const float4* c10 = (const float4*)(slice + 128 + (size_t)(y1*IMW + x0) * 256);
            const float4* c11 = (const float4*)(slice + 128 + (size_t)(y1*IMW + x1) * 256);
            float wp = sim[p];
            #pragma unroll
            for (int d4 = 0; d4 < 8; ++d4) {
                float4 va = c00[d4], vb = c01[d4], vc = c10[d4], vd = c11[d4];
                out[4*d4+0] += wp * (w00*va.x + w01*vb.x + w10*vc.x + w11*vd.x);
                out[4*d4+1] += wp * (w00*va.y + w01*vb.y + w10*vc.y + w11*vd.y);
                out[4*d4+2] += wp * (w00*va.z + w01*vb.z + w10*vc.z + w11*vd.z);
                out[4*d4+3] += wp * (w00*va.w + w01*vb.w + w10*vc.w + w11*vd.w);
            }
        }
        const float inv = 1.f / (ssum * (float)NCAM);   // softmax denom + /n
        #pragma unroll
        for (int d = 0; d < 32; ++d) out[d] *= inv;
    }

    // ---- reduce over cameras (8-lane groups, inactive lanes hold 0) ----
    #pragma unroll
    for (int d = 0; d < 32; ++d) {
        float v = out[d];
        v += __shfl_xor(v, 1, 8);
        v += __shfl_xor(v, 2, 8);
        v += __shfl_xor(v, 4, 8);
        out[d] = v;
    }
    if (s == 0) {
        float* orow = outw + ((size_t)b * 128 + m * 32) * HWQ + hw;
        #pragma unroll
        for (int d = 0; d < 32; ++d) orow[(size_t)d * HWQ] = out[d];
    }
}

// ---------------------------------------------------------------------------
extern "C" void kernel_launch(void* const* d_in, const int* in_sizes, int n_in,
                              void* d_out, int out_size, void* d_ws, size_t ws_size,
                              hipStream_t stream)
{
    const float* bev   = (const float*)d_in[0];   // [2,128,64,64]
    const float* img   = (const float*)d_in[1];   // [2,6,128,32,88]
    const float* Kin   = (const float*)d_in[2];   // [2,6,3,3]
    const float* Ein   = (const float*)d_in[3];   // [2,6,4,4]
    const float* wxy   = (const float*)d_in[4];   // [2,64,64]
    const float* wq    = (const float*)d_in[5];   // [128,128]
    const float* bq    = (const float*)d_in[6];
    const float* wkv   = (const float*)d_in[7];   // [256,128]
    const float* bkv   = (const float*)d_in[8];
    const float* woff1 = (const float*)d_in[9];   // [128,128]
    const float* boff1 = (const float*)d_in[10];
    const float* woff2 = (const float*)d_in[11];  // [16,128]
    const float* boff2 = (const float*)d_in[12];
    const float* wproj = (const float*)d_in[13];  // [128,128]
    const float* bproj = (const float*)d_in[14];
    float* out = (float*)d_out;

    float* ws    = (float*)d_ws;
    float* kvbuf = ws;                                   // 2*6*2816*256 = 8,650,752
    float* qb    = kvbuf + (size_t)2*NCAM*NPIX*256;      // 2*128*4096  = 1,048,576
    float* o1b   = qb    + (size_t)2*128*HWQ;            // 1,048,576
    float* offb  = o1b   + (size_t)2*128*HWQ;            // 2*16*4096   =   131,072
    float* gridb = offb  + (size_t)2*16*HWQ;             // 2*6*4096*2  =    98,304
    float* wbuf  = gridb + (size_t)2*NCAM*HWQ*2;         // 1,048,576
    // total 12,026,240 floats = 48.2 MB of d_ws

    // 1. camera projection grid
    grid_kernel<<<dim3(2*NCAM*HWQ/256), 256, 0, stream>>>(Ein, Kin, wxy, gridb);
    // 2. KV 1x1 conv -> pixel-major [b,n,pix,256]
    sgemm_kernel<<<dim3(NPIX/64, 256/64, 12), 256, 0, stream>>>(
        wkv, img, bkv, kvbuf, 256, NPIX, 128, 2, (long)128*NPIX, (long)NPIX*256);
    // 3. q projection
    sgemm_kernel<<<dim3(HWQ/64, 128/64, 2), 256, 0, stream>>>(
        wq, bev, bq, qb, 128, HWQ, 128, 0, (long)128*HWQ, (long)128*HWQ);
    // 4. offset MLP layer 1 (relu)
    sgemm_kernel<<<dim3(HWQ/64, 128/64, 2), 256, 0, stream>>>(
        woff1, bev, boff1, o1b, 128, HWQ, 128, 1, (long)128*HWQ, (long)128*HWQ);
    // 5. offset MLP layer 2 (M=16, partial tile guarded)
    sgemm_kernel<<<dim3(HWQ/64, 1, 2), 256, 0, stream>>>(
        woff2, o1b, boff2, offb, 16, HWQ, 128, 0, (long)128*HWQ, (long)16*HWQ);
    // 6. fused deformable sampling + attention
    attn_kernel<<<dim3(2*HWQ/8), 256, 0, stream>>>(kvbuf, qb, offb, gridb, wbuf);
    // 7. output projection
    sgemm_kernel<<<dim3(HWQ/64, 128/64, 2), 256, 0, stream>>>(
        wproj, wbuf, bproj, out, 128, HWQ, 128, 0, (long)128*HWQ, (long)128*HWQ);
}

// Round 2
// 179.352 us; speedup vs baseline: 1.8212x; 1.8212x over previous
//
#include <hip/hip_runtime.h>

#define HWQ  4096      // H*W = 64*64
#define NCAM 6
#define IMH  32
#define IMW  88
#define NPIX (IMH*IMW) // 2816

typedef unsigned short ushort_t;
typedef unsigned int   uint_t;

__device__ inline ushort_t f2bf(float f) {
    union { float f; uint_t u; } c; c.f = f;
    uint_t u = c.u + 0x7fffu + ((c.u >> 16) & 1u);   // round-to-nearest-even
    return (ushort_t)(u >> 16);
}
__device__ inline float bf_lo(uint_t u) { union { uint_t u; float f; } c; c.u = u << 16;        return c.f; }
__device__ inline float bf_hi(uint_t u) { union { uint_t u; float f; } c; c.u = u & 0xffff0000u; return c.f; }

// ---------------------------------------------------------------------------
// Generic batched SGEMM (64x64 tile): C[z] = A @ B[z] + bias.
// flags: 1 = relu, 2 = transposed store C[n*M+m] (pixel-major), 4 = B is [N,K].
// ---------------------------------------------------------------------------
__global__ __launch_bounds__(256) void sgemm_kernel(
    const float* __restrict__ A, const float* __restrict__ B,
    const float* __restrict__ bias, float* __restrict__ C,
    int M, int N, int K, int flags,
    long strideB, long strideC)
{
    __shared__ float As[16][68];
    __shared__ float Bs[16][68];

    const float* Bb = B + (size_t)blockIdx.z * strideB;
    float*       Cb = C + (size_t)blockIdx.z * strideC;

    const int tid = threadIdx.x;
    const int bm = blockIdx.y * 64, bn = blockIdx.x * 64;
    const int tm = ((tid >> 4) & 15) << 2;
    const int tn = (tid & 15) << 2;

    float acc[4][4] = {{0.f,0.f,0.f,0.f},{0.f,0.f,0.f,0.f},
                       {0.f,0.f,0.f,0.f},{0.f,0.f,0.f,0.f}};

    for (int k0 = 0; k0 < K; k0 += 16) {
        #pragma unroll
        for (int i = 0; i < 4; ++i) {         // A tile: 64m x 16k
            int idx = tid + i * 256;
            int mk = idx >> 4;
            int kk = idx & 15;
            int gm = bm + mk;
            As[kk][mk] = (gm < M) ? A[(size_t)gm * K + (k0 + kk)] : 0.f;
        }
        if (flags & 4) {                      // B^T: B is [N,K] row-major
            int nn = tid >> 2, k4 = (tid & 3) * 4;
            float4 bv = *(const float4*)&Bb[(size_t)(bn + nn) * K + (k0 + k4)];
            Bs[k4+0][nn] = bv.x; Bs[k4+1][nn] = bv.y;
            Bs[k4+2][nn] = bv.z; Bs[k4+3][nn] = bv.w;
        } else {
            #pragma unroll
            for (int i = 0; i < 4; ++i) {     // B tile: 16k x 64n
                int idx = tid + i * 256;
                int kk = idx >> 6;
                int nn = idx & 63;
                Bs[kk][nn] = Bb[(size_t)(k0 + kk) * N + (bn + nn)];
            }
        }
        __syncthreads();
        #pragma unroll
        for (int kk = 0; kk < 16; ++kk) {
            const float4 av = *(const float4*)&As[kk][tm];
            const float4 bv = *(const float4*)&Bs[kk][tn];
            const float a[4]  = {av.x, av.y, av.z, av.w};
            const float bb[4] = {bv.x, bv.y, bv.z, bv.w};
            #pragma unroll
            for (int i = 0; i < 4; ++i)
                #pragma unroll
                for (int j = 0; j < 4; ++j)
                    acc[i][j] += a[i] * bb[j];
        }
        __syncthreads();
    }

    if (flags & 2) {
        if (bm + tm < M) {                    // M multiple of 4 -> whole group valid
            const float b0 = bias[bm+tm+0], b1 = bias[bm+tm+1];
            const float b2 = bias[bm+tm+2], b3 = bias[bm+tm+3];
            #pragma unroll
            for (int j = 0; j < 4; ++j) {
                int gn = bn + tn + j;
                float4 v = make_float4(acc[0][j]+b0, acc[1][j]+b1,
                                       acc[2][j]+b2, acc[3][j]+b3);
                *(float4*)&Cb[(size_t)gn * M + (bm + tm)] = v;
            }
        }
    } else {
        #pragma unroll
        for (int i = 0; i < 4; ++i) {
            int gm = bm + tm + i;
            if (gm >= M) continue;
            float bi = bias[gm];
            float4 v = make_float4(acc[i][0]+bi, acc[i][1]+bi,
                                   acc[i][2]+bi, acc[i][3]+bi);
            if (flags & 1) {
                v.x = fmaxf(v.x, 0.f); v.y = fmaxf(v.y, 0.f);
                v.z = fmaxf(v.z, 0.f); v.w = fmaxf(v.w, 0.f);
            }
            *(float4*)&Cb[(size_t)gm * N + (bn + tn)] = v;
        }
    }
}

// ---------------------------------------------------------------------------
// KV GEMM: 128x128 tile, 8x8 microtile. C = wkv[256,128] @ img[z][128,2816].
// Epilogue: +bias, convert to bf16, store channel-INTERLEAVED pixel-major:
//   pixel row (256 ushorts): [k0,k1,v0,v1, k2,k3,v2,v3, ...]
//   K ch c -> ushort pos 4*(c>>1)+(c&1);  V ch c -> 4*(c>>1)+2+(c&1)
// ---------------------------------------------------------------------------
__global__ __launch_bounds__(256) void kvgemm_kernel(
    const float* __restrict__ A,      // wkv [256][128]
    const float* __restrict__ B,      // img [z][128][NPIX]
    const float* __restrict__ bias,   // [256]
    ushort_t* __restrict__ kvb)       // [z][NPIX][256] bf16 interleaved
{
    __shared__ float As[16][132];
    __shared__ float Bs[16][132];

    const int tid = threadIdx.x;
    const int bn = blockIdx.x * 128;
    const int bm = blockIdx.y * 128;
    const int z  = blockIdx.z;
    const float* Bb = B + (size_t)z * 128 * NPIX;

    const int tm = ((tid >> 4) & 15) << 2;   // 0..60
    const int tn = (tid & 15) << 2;

    float acc[8][8];
    #pragma unroll
    for (int i = 0; i < 8; ++i)
        #pragma unroll
        for (int j = 0; j < 8; ++j) acc[i][j] = 0.f;

    for (int k0 = 0; k0 < 128; k0 += 16) {
        #pragma unroll
        for (int i = 0; i < 2; ++i) {        // A: 128 rows x 16 k (transpose to LDS)
            int row = bm + i * 64 + (tid >> 2);
            int kc  = (tid & 3) * 4;
            float4 av = *(const float4*)&A[(size_t)row * 128 + (k0 + kc)];
            As[kc+0][i*64 + (tid>>2)] = av.x;
            As[kc+1][i*64 + (tid>>2)] = av.y;
            As[kc+2][i*64 + (tid>>2)] = av.z;
            As[kc+3][i*64 + (tid>>2)] = av.w;
        }
        #pragma unroll
        for (int i = 0; i < 2; ++i) {        // B: 16 k x 128 n
            int kr = i * 8 + (tid >> 5);
            float4 bv = *(const float4*)&Bb[(size_t)(k0 + kr) * NPIX + bn + (tid & 31) * 4];
            *(float4*)&Bs[kr][(tid & 31) * 4] = bv;
        }
        __syncthreads();
        #pragma unroll
        for (int kk = 0; kk < 16; ++kk) {
            float4 a0 = *(const float4*)&As[kk][tm];
            float4 a1 = *(const float4*)&As[kk][tm + 64];
            float4 b0 = *(const float4*)&Bs[kk][tn];
            float4 b1 = *(const float4*)&Bs[kk][tn + 64];
            float am[8] = {a0.x,a0.y,a0.z,a0.w, a1.x,a1.y,a1.z,a1.w};
            float bv[8] = {b0.x,b0.y,b0.z,b0.w, b1.x,b1.y,b1.z,b1.w};
            #pragma unroll
            for (int i = 0; i < 8; ++i)
                #pragma unroll
                for (int j = 0; j < 8; ++j)
                    acc[i][j] += am[i] * bv[j];
        }
        __syncthreads();
    }

    #pragma unroll
    for (int io = 0; io < 2; ++io) {
        const int o4  = bm + tm + io * 64;   // 4 consecutive output channels
        const int c   = o4 & 127;
        const int pos0 = ((c >> 1) << 2) + ((o4 >= 128) ? 2 : 0);
        const float bs0 = bias[o4+0], bs1 = bias[o4+1];
        const float bs2 = bias[o4+2], bs3 = bias[o4+3];
        #pragma unroll
        for (int jo = 0; jo < 2; ++jo)
            #pragma unroll
            for (int jj = 0; jj < 4; ++jj) {
                int gn = bn + tn + jo * 64 + jj;
                int j  = jo * 4 + jj;
                ushort_t u0 = f2bf(acc[io*4+0][j] + bs0);
                ushort_t u1 = f2bf(acc[io*4+1][j] + bs1);
                ushort_t u2 = f2bf(acc[io*4+2][j] + bs2);
                ushort_t u3 = f2bf(acc[io*4+3][j] + bs3);
                ushort_t* dst = kvb + ((size_t)z * NPIX + gn) * 256;
                *(uint_t*)(dst + pos0)     = (uint_t)u0 | ((uint_t)u1 << 16);
                *(uint_t*)(dst + pos0 + 4) = (uint_t)u2 | ((uint_t)u3 << 16);
            }
    }
}

// ---------------------------------------------------------------------------
// Camera projection: grid[b][n][hw][2]
// ---------------------------------------------------------------------------
__global__ __launch_bounds__(256) void grid_kernel(
    const float* __restrict__ E, const float* __restrict__ Km,
    const float* __restrict__ wxy, float* __restrict__ gridbuf)
{
    int idx = blockIdx.x * 256 + threadIdx.x;
    int hw = idx & (HWQ - 1);
    int bn = idx >> 12;
    float x = wxy[hw], y = wxy[HWQ + hw];
    const float* e = E + bn * 16;
    const float* k = Km + bn * 9;
    float cam0 = e[0]*x + e[1]*y + e[3];
    float cam1 = e[4]*x + e[5]*y + e[7];
    float cam2 = e[8]*x + e[9]*y + e[11];
    float px = k[0]*cam0 + k[1]*cam1 + k[2]*cam2;
    float py = k[3]*cam0 + k[4]*cam1 + k[5]*cam2;
    float pz = k[6]*cam0 + k[7]*cam1 + k[8]*cam2;
    pz = fmaxf(pz, 1e-6f);
    float u = px / pz, v = py / pz;
    float gx = u / (float)(IMW - 1) * 2.f - 1.f;
    float gy = v / (float)(IMH - 1) * 2.f - 1.f;
    gridbuf[(size_t)idx * 2 + 0] = gx;
    gridbuf[(size_t)idx * 2 + 1] = gy;
}

// ---------------------------------------------------------------------------
// Fused deformable sampling + attention. Wave = one query q=(b,hw).
// Lane l: K channels {2l, 2l+1}, V channels {2l, 2l+1}; head h = l>>4.
// Each bilinear corner = ONE coalesced 512B wave-load (uint2 per lane).
// Online softmax with unnormalized exp (|sim| small -> safe).
// ---------------------------------------------------------------------------
__global__ __launch_bounds__(256) void attn_kernel(
    const ushort_t* __restrict__ kvb,  // [b*6][NPIX][256] bf16 interleaved
    const float* __restrict__ qb,      // [b][hw][128] pixel-major
    const float* __restrict__ offb,    // [b][hw][16]  pixel-major
    const float* __restrict__ gridb,   // [b][n][hw][2]
    float* __restrict__ wbuf)          // [b][hw][128] pixel-major
{
    const int lane = threadIdx.x & 63;
    const int wv   = threadIdx.x >> 6;
    const int qg   = blockIdx.x * 4 + wv;     // b*4096 + hw
    const int b    = qg >> 12;
    const int hw   = qg & (HWQ - 1);

    const float2 qv = *(const float2*)&qb[(size_t)qg * 128 + lane * 2];

    const float4* offp = (const float4*)&offb[(size_t)qg * 16];
    float4 o0 = offp[0], o1 = offp[1], o2 = offp[2], o3 = offp[3];
    const float off[16] = {o0.x,o0.y,o0.z,o0.w, o1.x,o1.y,o1.z,o1.w,
                           o2.x,o2.y,o2.z,o2.w, o3.x,o3.y,o3.z,o3.w};

    float out0 = 0.f, out1 = 0.f;

    for (int n = 0; n < NCAM; ++n) {
        const float2 g = *(const float2*)&gridb[(((size_t)b * NCAM + n) * HWQ + hw) * 2];
        const ushort_t* lbase = kvb + ((size_t)(b * NCAM + n)) * NPIX * 256 + lane * 4;
        float ssum = 0.f, vac0 = 0.f, vac1 = 0.f;
        #pragma unroll
        for (int p = 0; p < 8; ++p) {
            float sx = fminf(fmaxf(g.x + off[2*p],   -1.f), 1.f);
            float sy = fminf(fmaxf(g.y + off[2*p+1], -1.f), 1.f);
            float ixf = (sx + 1.f) * (0.5f * (float)(IMW - 1));
            float iyf = (sy + 1.f) * (0.5f * (float)(IMH - 1));
            float x0f = floorf(ixf), y0f = floorf(iyf);
            float fx = ixf - x0f, fy = iyf - y0f;
            int x0 = (int)x0f, y0 = (int)y0f;
            int x1 = min(x0 + 1, IMW - 1);
            int y1 = min(y0 + 1, IMH - 1);
            int r0 = y0 * IMW, r1 = y1 * IMW;
            float w00 = (1.f-fx)*(1.f-fy), w01 = fx*(1.f-fy);
            float w10 = (1.f-fx)*fy,       w11 = fx*fy;
            uint2 c00 = *(const uint2*)(lbase + (size_t)(r0 + x0) * 256);
            uint2 c01 = *(const uint2*)(lbase + (size_t)(r0 + x1) * 256);
            uint2 c10 = *(const uint2*)(lbase + (size_t)(r1 + x0) * 256);
            uint2 c11 = *(const uint2*)(lbase + (size_t)(r1 + x1) * 256);
            // K bilinear (2 channels) + partial dot
            float k0 = w00*bf_lo(c00.x) + w01*bf_lo(c01.x) + w10*bf_lo(c10.x) + w11*bf_lo(c11.x);
            float k1 = w00*bf_hi(c00.x) + w01*bf_hi(c01.x) + w10*bf_hi(c10.x) + w11*bf_hi(c11.x);
            float s = qv.x * k0 + qv.y * k1;
            s += __shfl_xor(s, 1, 16);
            s += __shfl_xor(s, 2, 16);
            s += __shfl_xor(s, 4, 16);
            s += __shfl_xor(s, 8, 16);
            float e = __expf(s);
            ssum += e;
            // V bilinear (2 channels), weighted accumulate
            float v0 = w00*bf_lo(c00.y) + w01*bf_lo(c01.y) + w10*bf_lo(c10.y) + w11*bf_lo(c11.y);
            float v1 = w00*bf_hi(c00.y) + w01*bf_hi(c01.y) + w10*bf_hi(c10.y) + w11*bf_hi(c11.y);
            vac0 += e * v0;
            vac1 += e * v1;
        }
        float inv = 1.f / ssum;
        out0 += vac0 * inv;
        out1 += vac1 * inv;
    }
    out0 *= (1.f / (float)NCAM);
    out1 *= (1.f / (float)NCAM);
    *(float2*)&wbuf[(size_t)qg * 128 + lane * 2] = make_float2(out0, out1);
}

// ---------------------------------------------------------------------------
extern "C" void kernel_launch(void* const* d_in, const int* in_sizes, int n_in,
                              void* d_out, int out_size, void* d_ws, size_t ws_size,
                              hipStream_t stream)
{
    const float* bev   = (const float*)d_in[0];
    const float* img   = (const float*)d_in[1];
    const float* Kin   = (const float*)d_in[2];
    const float* Ein   = (const float*)d_in[3];
    const float* wxy   = (const float*)d_in[4];
    const float* wq    = (const float*)d_in[5];
    const float* bq    = (const float*)d_in[6];
    const float* wkv   = (const float*)d_in[7];
    const float* bkv   = (const float*)d_in[8];
    const float* woff1 = (const float*)d_in[9];
    const float* boff1 = (const float*)d_in[10];
    const float* woff2 = (const float*)d_in[11];
    const float* boff2 = (const float*)d_in[12];
    const float* wproj = (const float*)d_in[13];
    const float* bproj = (const float*)d_in[14];
    float* out = (float*)d_out;

    ushort_t* kvb = (ushort_t*)d_ws;                     // 12*2816*256 u16 = 17.3 MB
    float* fws   = (float*)((char*)d_ws + (size_t)12 * NPIX * 256 * sizeof(ushort_t));
    float* qb    = fws;                                  // 2*4096*128
    float* o1b   = qb    + (size_t)2 * HWQ * 128;        // 2*128*4096 (channel-major)
    float* offb  = o1b   + (size_t)2 * 128 * HWQ;        // 2*4096*16
    float* gridb = offb  + (size_t)2 * HWQ * 16;         // 2*6*4096*2
    float* wbuf  = gridb + (size_t)2 * NCAM * HWQ * 2;   // 2*4096*128

    // 1. camera projection grid
    grid_kernel<<<dim3(2*NCAM*HWQ/256), 256, 0, stream>>>(Ein, Kin, wxy, gridb);
    // 2. KV 1x1 conv -> bf16 interleaved pixel-major
    kvgemm_kernel<<<dim3(NPIX/128, 2, 12), 256, 0, stream>>>(wkv, img, bkv, kvb);
    // 3. q projection -> pixel-major [b][hw][128]
    sgemm_kernel<<<dim3(HWQ/64, 128/64, 2), 256, 0, stream>>>(
        wq, bev, bq, qb, 128, HWQ, 128, 2, (long)128*HWQ, (long)HWQ*128);
    // 4. offset MLP layer 1 (relu, channel-major)
    sgemm_kernel<<<dim3(HWQ/64, 128/64, 2), 256, 0, stream>>>(
        woff1, bev, boff1, o1b, 128, HWQ, 128, 1, (long)128*HWQ, (long)128*HWQ);
    // 5. offset MLP layer 2 -> pixel-major [b][hw][16]
    sgemm_kernel<<<dim3(HWQ/64, 1, 2), 256, 0, stream>>>(
        woff2, o1b, boff2, offb, 16, HWQ, 128, 2, (long)128*HWQ, (long)HWQ*16);
    // 6. fused deformable sampling + attention (wave per query)
    attn_kernel<<<dim3(2*HWQ/4), 256, 0, stream>>>(kvb, qb, offb, gridb, wbuf);
    // 7. output projection (B^T load from pixel-major wbuf, channel-major store)
    sgemm_kernel<<<dim3(HWQ/64, 128/64, 2), 256, 0, stream>>>(
        wproj, wbuf, bproj, out, 128, HWQ, 128, 4, (long)HWQ*128, (long)128*HWQ);
}

// Round 4
// 176.671 us; speedup vs baseline: 1.8489x; 1.0152x over previous
//
#include <hip/hip_runtime.h>

#define HWQ  4096      // H*W = 64*64
#define NCAM 6
#define IMH  32
#define IMW  88
#define NPIX (IMH*IMW) // 2816

typedef unsigned short ushort_t;
typedef unsigned int   uint_t;
typedef __fp16 h2 __attribute__((ext_vector_type(2)));

union UH { uint_t u; h2 h; };
__device__ inline h2 u2h(uint_t x){ UH c; c.u = x; return c.h; }
__device__ inline uint_t packrtz(float a, float b){
    UH c; c.h = __builtin_amdgcn_cvt_pkrtz(a, b); return c.u;
}

// ---------------------------------------------------------------------------
// f32 GEMM -> f16 output, pixel-on-rows orientation (coalesced f16 stores).
// A: [128+ ch][128 k] (ch0 = blockIdx.y*128), B: [z][128 k][N pix].
// mode 0: KV interleaved row of 256 u16: K ch c -> u16 4*(c>>1)+(c&1),
//         V ch c -> +2  (blockIdx.y: 0=K half, 1=V half)
// mode 1: plain f16 row of rowU u16 (ch c -> u16 c)
// ---------------------------------------------------------------------------
__global__ __launch_bounds__(256) void kvq_gemm(
    const float* __restrict__ A, const float* __restrict__ B,
    const float* __restrict__ bias, ushort_t* __restrict__ outp,
    int N, long rowsZ, int rowU, int mode)
{
    __shared__ float Cs[16][132];  // A^T tile [k][ch]
    __shared__ float Ps[16][132];  // B tile   [k][pix]
    const int tid = threadIdx.x;
    const int px0 = blockIdx.x * 128;
    const int yh  = blockIdx.y;
    const int ch0 = yh * 128;
    const int z   = blockIdx.z;
    const float* Bb = B + (size_t)z * 128 * N;

    const int tm = ((tid >> 4) & 15) << 2;   // pixel frag
    const int tn = (tid & 15) << 2;          // channel frag

    float acc[8][8] = {};

    for (int k0 = 0; k0 < 128; k0 += 16) {
        #pragma unroll
        for (int i = 0; i < 2; ++i) {        // A -> Cs[k][ch] (transpose)
            int row = ch0 + i * 64 + (tid >> 2);
            int kc  = (tid & 3) * 4;
            float4 av = *(const float4*)&A[(size_t)row * 128 + k0 + kc];
            int cc = i * 64 + (tid >> 2);
            Cs[kc+0][cc] = av.x; Cs[kc+1][cc] = av.y;
            Cs[kc+2][cc] = av.z; Cs[kc+3][cc] = av.w;
        }
        #pragma unroll
        for (int i = 0; i < 2; ++i) {        // B -> Ps[k][pix]
            int kr = i * 8 + (tid >> 5);
            float4 bv = *(const float4*)&Bb[(size_t)(k0 + kr) * N + px0 + (tid & 31) * 4];
            *(float4*)&Ps[kr][(tid & 31) * 4] = bv;
        }
        __syncthreads();
        #pragma unroll
        for (int kk = 0; kk < 16; ++kk) {
            float4 p0 = *(const float4*)&Ps[kk][tm];
            float4 p1 = *(const float4*)&Ps[kk][tm + 64];
            float4 c0 = *(const float4*)&Cs[kk][tn];
            float4 c1 = *(const float4*)&Cs[kk][tn + 64];
            float pm[8] = {p0.x,p0.y,p0.z,p0.w, p1.x,p1.y,p1.z,p1.w};
            float cm[8] = {c0.x,c0.y,c0.z,c0.w, c1.x,c1.y,c1.z,c1.w};
            #pragma unroll
            for (int i = 0; i < 8; ++i)
                #pragma unroll
                for (int j = 0; j < 8; ++j)
                    acc[i][j] += pm[i] * cm[j];
        }
        __syncthreads();
    }

    float bs[8];
    #pragma unroll
    for (int j = 0; j < 8; ++j) bs[j] = bias[ch0 + tn + (j & 3) + (j >> 2) * 64];
    #pragma unroll
    for (int i = 0; i < 8; ++i) {
        int gp = px0 + tm + (i & 3) + (i >> 2) * 64;
        ushort_t* dst = outp + ((size_t)z * rowsZ + gp) * rowU;
        uint_t u0 = packrtz(acc[i][0] + bs[0], acc[i][1] + bs[1]);
        uint_t u1 = packrtz(acc[i][2] + bs[2], acc[i][3] + bs[3]);
        uint_t u2 = packrtz(acc[i][4] + bs[4], acc[i][5] + bs[5]);
        uint_t u3 = packrtz(acc[i][6] + bs[6], acc[i][7] + bs[7]);
        if (mode == 0) {
            int o = 2 * tn + 2 * yh;
            *(uint_t*)(dst + o)       = u0;
            *(uint_t*)(dst + o + 4)   = u1;
            *(uint_t*)(dst + o + 128) = u2;
            *(uint_t*)(dst + o + 132) = u3;
        } else {
            *(uint2*)(dst + tn)      = make_uint2(u0, u1);
            *(uint2*)(dst + tn + 64) = make_uint2(u2, u3);
        }
    }
}

// ---------------------------------------------------------------------------
// f32 GEMM, M=128, channel-major f32 out. flags: 1 = relu, 4 = B is [pix][128].
// ---------------------------------------------------------------------------
__global__ __launch_bounds__(256) void sgemm128f(
    const float* __restrict__ A, const float* __restrict__ B,
    const float* __restrict__ bias, float* __restrict__ C,
    int N, int flags, long strideB, long strideC)
{
    __shared__ float As[16][132];
    __shared__ float Bs[16][132];
    const int tid = threadIdx.x;
    const int px0 = blockIdx.x * 128;
    const int z = blockIdx.z;
    const float* Bb = B + (size_t)z * strideB;
    float*       Cb = C + (size_t)z * strideC;
    const int tm = ((tid >> 4) & 15) << 2;   // ch frag
    const int tn = (tid & 15) << 2;          // pix frag

    float acc[8][8] = {};

    for (int k0 = 0; k0 < 128; k0 += 16) {
        #pragma unroll
        for (int i = 0; i < 2; ++i) {        // A -> As[k][ch]
            int row = i * 64 + (tid >> 2);
            int kc = (tid & 3) * 4;
            float4 av = *(const float4*)&A[(size_t)row * 128 + k0 + kc];
            int cc = i * 64 + (tid >> 2);
            As[kc+0][cc] = av.x; As[kc+1][cc] = av.y;
            As[kc+2][cc] = av.z; As[kc+3][cc] = av.w;
        }
        if (flags & 4) {                     // B^T: [pix][128]
            #pragma unroll
            for (int i = 0; i < 2; ++i) {
                int pix = px0 + i * 64 + (tid >> 2);
                int kc = (tid & 3) * 4;
                float4 bv = *(const float4*)&Bb[(size_t)pix * 128 + k0 + kc];
                int cc = i * 64 + (tid >> 2);
                Bs[kc+0][cc] = bv.x; Bs[kc+1][cc] = bv.y;
                Bs[kc+2][cc] = bv.z; Bs[kc+3][cc] = bv.w;
            }
        } else {
            #pragma unroll
            for (int i = 0; i < 2; ++i) {
                int kr = i * 8 + (tid >> 5);
                float4 bv = *(const float4*)&Bb[(size_t)(k0 + kr) * N + px0 + (tid & 31) * 4];
                *(float4*)&Bs[kr][(tid & 31) * 4] = bv;
            }
        }
        __syncthreads();
        #pragma unroll
        for (int kk = 0; kk < 16; ++kk) {
            float4 a0 = *(const float4*)&As[kk][tm];
            float4 a1 = *(const float4*)&As[kk][tm + 64];
            float4 b0 = *(const float4*)&Bs[kk][tn];
            float4 b1 = *(const float4*)&Bs[kk][tn + 64];
            float am[8] = {a0.x,a0.y,a0.z,a0.w, a1.x,a1.y,a1.z,a1.w};
            float bm[8] = {b0.x,b0.y,b0.z,b0.w, b1.x,b1.y,b1.z,b1.w};
            #pragma unroll
            for (int i = 0; i < 8; ++i)
                #pragma unroll
                for (int j = 0; j < 8; ++j)
                    acc[i][j] += am[i] * bm[j];
        }
        __syncthreads();
    }

    #pragma unroll
    for (int i = 0; i < 8; ++i) {
        int gm = tm + (i & 3) + (i >> 2) * 64;
        float bi = bias[gm];
        float4 v0 = make_float4(acc[i][0]+bi, acc[i][1]+bi, acc[i][2]+bi, acc[i][3]+bi);
        float4 v1 = make_float4(acc[i][4]+bi, acc[i][5]+bi, acc[i][6]+bi, acc[i][7]+bi);
        if (flags & 1) {
            v0.x=fmaxf(v0.x,0.f); v0.y=fmaxf(v0.y,0.f); v0.z=fmaxf(v0.z,0.f); v0.w=fmaxf(v0.w,0.f);
            v1.x=fmaxf(v1.x,0.f); v1.y=fmaxf(v1.y,0.f); v1.z=fmaxf(v1.z,0.f); v1.w=fmaxf(v1.w,0.f);
        }
        *(float4*)&Cb[(size_t)gm * N + px0 + tn]      = v0;
        *(float4*)&Cb[(size_t)gm * N + px0 + tn + 64] = v1;
    }
}

// ---------------------------------------------------------------------------
// Generic 64x64 SGEMM (used for off2, M=16). flags: 2 = transposed store.
// ---------------------------------------------------------------------------
__global__ __launch_bounds__(256) void sgemm_kernel(
    const float* __restrict__ A, const float* __restrict__ B,
    const float* __restrict__ bias, float* __restrict__ C,
    int M, int N, int K, int flags,
    long strideB, long strideC)
{
    __shared__ float As[16][68];
    __shared__ float Bs[16][68];
    const float* Bb = B + (size_t)blockIdx.z * strideB;
    float*       Cb = C + (size_t)blockIdx.z * strideC;
    const int tid = threadIdx.x;
    const int bm = blockIdx.y * 64, bn = blockIdx.x * 64;
    const int tm = ((tid >> 4) & 15) << 2;
    const int tn = (tid & 15) << 2;

    float acc[4][4] = {};

    for (int k0 = 0; k0 < K; k0 += 16) {
        #pragma unroll
        for (int i = 0; i < 4; ++i) {
            int idx = tid + i * 256;
            int mk = idx >> 4, kk = idx & 15;
            int gm = bm + mk;
            As[kk][mk] = (gm < M) ? A[(size_t)gm * K + (k0 + kk)] : 0.f;
        }
        #pragma unroll
        for (int i = 0; i < 4; ++i) {
            int idx = tid + i * 256;
            int kk = idx >> 6, nn = idx & 63;
            Bs[kk][nn] = Bb[(size_t)(k0 + kk) * N + (bn + nn)];
        }
        __syncthreads();
        #pragma unroll
        for (int kk = 0; kk < 16; ++kk) {
            const float4 av = *(const float4*)&As[kk][tm];
            const float4 bv = *(const float4*)&Bs[kk][tn];
            const float a[4]  = {av.x, av.y, av.z, av.w};
            const float bb[4] = {bv.x, bv.y, bv.z, bv.w};
            #pragma unroll
            for (int i = 0; i < 4; ++i)
                #pragma unroll
                for (int j = 0; j < 4; ++j)
                    acc[i][j] += a[i] * bb[j];
        }
        __syncthreads();
    }

    if (flags & 2) {
        if (bm + tm < M) {
            const float b0 = bias[bm+tm+0], b1 = bias[bm+tm+1];
            const float b2 = bias[bm+tm+2], b3 = bias[bm+tm+3];
            #pragma unroll
            for (int j = 0; j < 4; ++j) {
                int gn = bn + tn + j;
                float4 v = make_float4(acc[0][j]+b0, acc[1][j]+b1,
                                       acc[2][j]+b2, acc[3][j]+b3);
                *(float4*)&Cb[(size_t)gn * M + (bm + tm)] = v;
            }
        }
    } else {
        #pragma unroll
        for (int i = 0; i < 4; ++i) {
            int gm = bm + tm + i;
            if (gm >= M) continue;
            float bi = bias[gm];
            float4 v = make_float4(acc[i][0]+bi, acc[i][1]+bi,
                                   acc[i][2]+bi, acc[i][3]+bi);
            if (flags & 1) {
                v.x = fmaxf(v.x, 0.f); v.y = fmaxf(v.y, 0.f);
                v.z = fmaxf(v.z, 0.f); v.w = fmaxf(v.w, 0.f);
            }
            *(float4*)&Cb[(size_t)gm * N + (bn + tn)] = v;
        }
    }
}

// ---------------------------------------------------------------------------
// Fused camera-projection + deformable sampling + attention.
// Wave = one query (b,hw). Lane l: K ch {2l,2l+1}, V ch {2l,2l+1}, head l>>4.
// KV f16 interleaved: pixel row u16[256] = [k0,k1,v0,v1, k2,k3,v2,v3, ...].
// Bilinear in packed f16 (v_pk_fma), qk dot via v_dot2_f32_f16.
// ---------------------------------------------------------------------------
__global__ __launch_bounds__(256) void attn_kernel(
    const ushort_t* __restrict__ kvb,   // [12][NPIX][256] f16 interleaved
    const ushort_t* __restrict__ qb,    // [2*HWQ][128] f16 pixel-major
    const float* __restrict__ offb,     // [2*HWQ][16]
    const float* __restrict__ Ein,      // [2,6,4,4]
    const float* __restrict__ Kin,      // [2,6,3,3]
    const float* __restrict__ wxy,      // [2,64,64]
    float* __restrict__ wbuf)           // [2*HWQ][128]
{
    const int lane = threadIdx.x & 63;
    const int wv   = threadIdx.x >> 6;
    const int qg   = blockIdx.x * 4 + wv;
    const int b    = qg >> 12;
    const int hw   = qg & (HWQ - 1);

    const uint_t qu = ((const uint_t*)qb)[(size_t)qg * 64 + lane];
    const h2 qh = u2h(qu);

    const float4* offp = (const float4*)&offb[(size_t)qg * 16];
    float4 o0 = offp[0], o1 = offp[1], o2 = offp[2], o3 = offp[3];
    const float off[16] = {o0.x,o0.y,o0.z,o0.w, o1.x,o1.y,o1.z,o1.w,
                           o2.x,o2.y,o2.z,o2.w, o3.x,o3.y,o3.z,o3.w};

    const float wx = wxy[hw], wy = wxy[HWQ + hw];

    float out0 = 0.f, out1 = 0.f;

    for (int n = 0; n < NCAM; ++n) {
        const float* e  = Ein + (size_t)(b * NCAM + n) * 16;
        const float* km = Kin + (size_t)(b * NCAM + n) * 9;
        float c0 = e[0]*wx + e[1]*wy + e[3];
        float c1 = e[4]*wx + e[5]*wy + e[7];
        float c2 = e[8]*wx + e[9]*wy + e[11];
        float pxx = km[0]*c0 + km[1]*c1 + km[2]*c2;
        float pyy = km[3]*c0 + km[4]*c1 + km[5]*c2;
        float pzz = km[6]*c0 + km[7]*c1 + km[8]*c2;
        pzz = fmaxf(pzz, 1e-6f);
        float gx = (pxx / pzz) * (2.f / (float)(IMW - 1)) - 1.f;
        float gy = (pyy / pzz) * (2.f / (float)(IMH - 1)) - 1.f;

        const char* cb = (const char*)kvb
                       + ((size_t)(b * NCAM + n) * NPIX) * 512 + (size_t)lane * 8;
        float ssum = 0.f, vac0 = 0.f, vac1 = 0.f;
        #pragma unroll
        for (int p = 0; p < 8; ++p) {
            float sx = fminf(fmaxf(gx + off[2*p],   -1.f), 1.f);
            float sy = fminf(fmaxf(gy + off[2*p+1], -1.f), 1.f);
            float ixf = (sx + 1.f) * (0.5f * (float)(IMW - 1));
            float iyf = (sy + 1.f) * (0.5f * (float)(IMH - 1));
            float x0f = floorf(ixf), y0f = floorf(iyf);
            float fx = ixf - x0f, fy = iyf - y0f;
            int x0 = (int)x0f, y0 = (int)y0f;
            int x1 = min(x0 + 1, IMW - 1);
            int y1 = min(y0 + 1, IMH - 1);
            int r0 = y0 * IMW, r1 = y1 * IMW;
            float gxw = 1.f - fx, gyw = 1.f - fy;
            float w00 = gxw * gyw, w01 = fx * gyw;
            float w10 = gxw * fy,  w11 = fx * fy;
            h2 w00h = __builtin_amdgcn_cvt_pkrtz(w00, w00);
            h2 w01h = __builtin_amdgcn_cvt_pkrtz(w01, w01);
            h2 w10h = __builtin_amdgcn_cvt_pkrtz(w10, w10);
            h2 w11h = __builtin_amdgcn_cvt_pkrtz(w11, w11);

            uint2 a00 = *(const uint2*)(cb + (size_t)(r0 + x0) * 512);
            uint2 a01 = *(const uint2*)(cb + (size_t)(r0 + x1) * 512);
            uint2 a10 = *(const uint2*)(cb + (size_t)(r1 + x0) * 512);
            uint2 a11 = *(const uint2*)(cb + (size_t)(r1 + x1) * 512);

            h2 kb = u2h(a00.x)*w00h + u2h(a01.x)*w01h + u2h(a10.x)*w10h + u2h(a11.x)*w11h;
            h2 vb = u2h(a00.y)*w00h + u2h(a01.y)*w01h + u2h(a10.y)*w10h + u2h(a11.y)*w11h;

#if __has_builtin(__builtin_amdgcn_fdot2)
            float s = __builtin_amdgcn_fdot2(qh, kb, 0.f, false);
#else
            float s = (float)qh.x * (float)kb.x + (float)qh.y * (float)kb.y;
#endif
            s += __shfl_xor(s, 1, 16);
            s += __shfl_xor(s, 2, 16);
            s += __shfl_xor(s, 4, 16);
            s += __shfl_xor(s, 8, 16);
            float es = __expf(s);
            ssum += es;
            vac0 += es * (float)vb.x;
            vac1 += es * (float)vb.y;
        }
        float inv = 1.f / ssum;
        out0 += vac0 * inv;
        out1 += vac1 * inv;
    }
    out0 *= (1.f / (float)NCAM);
    out1 *= (1.f / (float)NCAM);
    *(float2*)&wbuf[(size_t)qg * 128 + lane * 2] = make_float2(out0, out1);
}

// ---------------------------------------------------------------------------
extern "C" void kernel_launch(void* const* d_in, const int* in_sizes, int n_in,
                              void* d_out, int out_size, void* d_ws, size_t ws_size,
                              hipStream_t stream)
{
    const float* bev   = (const float*)d_in[0];
    const float* img   = (const float*)d_in[1];
    const float* Kin   = (const float*)d_in[2];
    const float* Ein   = (const float*)d_in[3];
    const float* wxy   = (const float*)d_in[4];
    const float* wq    = (const float*)d_in[5];
    const float* bq    = (const float*)d_in[6];
    const float* wkv   = (const float*)d_in[7];
    const float* bkv   = (const float*)d_in[8];
    const float* woff1 = (const float*)d_in[9];
    const float* boff1 = (const float*)d_in[10];
    const float* woff2 = (const float*)d_in[11];
    const float* boff2 = (const float*)d_in[12];
    const float* wproj = (const float*)d_in[13];
    const float* bproj = (const float*)d_in[14];
    float* out = (float*)d_out;

    ushort_t* kvb = (ushort_t*)d_ws;                        // 12*2816*256 u16 = 17.3 MB
    ushort_t* qb  = kvb + (size_t)12 * NPIX * 256;          // 2*4096*128 u16  =  2.0 MB
    float* fws  = (float*)(qb + (size_t)2 * HWQ * 128);
    float* o1b  = fws;                                      // 2*128*4096 f32
    float* offb = o1b  + (size_t)2 * 128 * HWQ;             // 2*4096*16  f32
    float* wbuf = offb + (size_t)2 * HWQ * 16;              // 2*4096*128 f32

    // 1. KV 1x1 conv -> f16 interleaved pixel-major (y: 0=K half, 1=V half)
    kvq_gemm<<<dim3(NPIX/128, 2, 12), 256, 0, stream>>>(
        wkv, img, bkv, kvb, NPIX, (long)NPIX, 256, 0);
    // 2. q projection -> f16 pixel-major [qg][128]
    kvq_gemm<<<dim3(HWQ/128, 1, 2), 256, 0, stream>>>(
        wq, bev, bq, qb, HWQ, (long)HWQ, 128, 1);
    // 3. offset MLP layer 1 (relu, channel-major f32)
    sgemm128f<<<dim3(HWQ/128, 1, 2), 256, 0, stream>>>(
        woff1, bev, boff1, o1b, HWQ, 1, (long)128*HWQ, (long)128*HWQ);
    // 4. offset MLP layer 2 -> pixel-major [qg][16] f32
    sgemm_kernel<<<dim3(HWQ/64, 1, 2), 256, 0, stream>>>(
        woff2, o1b, boff2, offb, 16, HWQ, 128, 2, (long)128*HWQ, (long)HWQ*16);
    // 5. fused projection + sampling + attention
    attn_kernel<<<dim3(2*HWQ/4), 256, 0, stream>>>(
        kvb, qb, offb, Ein, Kin, wxy, wbuf);
    // 6. output projection (B^T from pixel-major wbuf, channel-major f32 out)
    sgemm128f<<<dim3(HWQ/128, 1, 2), 256, 0, stream>>>(
        wproj, wbuf, bproj, out, HWQ, 4, (long)HWQ*128, (long)128*HWQ);
}

// Round 5
// 127.384 us; speedup vs baseline: 2.5642x; 1.3869x over previous
//
#include <hip/hip_runtime.h>

#define HWQ  4096      // H*W = 64*64
#define NCAM 6
#define IMH  32
#define IMW  88
#define NPIX (IMH*IMW) // 2816

typedef unsigned short ushort_t;
typedef unsigned int   uint_t;
typedef __fp16 h2   __attribute__((ext_vector_type(2)));
typedef __fp16 f16x8 __attribute__((ext_vector_type(8)));
typedef float  f32x4 __attribute__((ext_vector_type(4)));

union UH { uint_t u; h2 h; };
__device__ inline h2 u2h(uint_t x){ UH c; c.u = x; return c.h; }
__device__ inline uint_t packrtz(float a, float b){
    UH c; c.h = __builtin_amdgcn_cvt_pkrtz(a, b); return c.u;
}

// butterfly add within 16-lane rows, VALU-only (DPP)
#define DPPADD(s, ctrl) { \
    int _x = __builtin_amdgcn_update_dpp(0, __float_as_int(s), ctrl, 0xF, 0xF, true); \
    s += __int_as_float(_x); }

// ---------------------------------------------------------------------------
// img [z][128ch][2816px] f32  ->  imgT [z][2816px][128ch] f16
// ---------------------------------------------------------------------------
__global__ __launch_bounds__(256) void imgT_kernel(
    const float* __restrict__ img, ushort_t* __restrict__ imgT)
{
    __shared__ ushort_t T[64][136];          // [px][ch], pad 8
    const int t = threadIdx.x;
    const int z = blockIdx.y;
    const int px0 = blockIdx.x * 64;
    const float* src = img + (size_t)z * 128 * NPIX;
    #pragma unroll
    for (int i = 0; i < 8; ++i) {
        int f4 = t + i * 256;                // 0..2047
        int ch = f4 >> 4, part = f4 & 15;
        float4 v = *(const float4*)&src[(size_t)ch * NPIX + px0 + part * 4];
        uint_t p01 = packrtz(v.x, v.y), p23 = packrtz(v.z, v.w);
        T[part*4+0][ch] = (ushort_t)p01;
        T[part*4+1][ch] = (ushort_t)(p01 >> 16);
        T[part*4+2][ch] = (ushort_t)p23;
        T[part*4+3][ch] = (ushort_t)(p23 >> 16);
    }
    __syncthreads();
    #pragma unroll
    for (int i = 0; i < 4; ++i) {
        int idx = t + i * 256;               // 0..1023
        int px = idx >> 4, c8 = (idx & 15) * 8;
        *(uint4*)&imgT[((size_t)z * NPIX + px0 + px) * 128 + c8] = *(const uint4*)&T[px][c8];
    }
}

// ---------------------------------------------------------------------------
// KV 1x1 conv via f16 MFMA: C[256ch][2816px] = wkv @ imgT^T, per z.
// Output f16 channel-interleaved pixel rows: u16[256] = [K0,K1,V0,V1,K2,K3,V2,V3,..]
// ---------------------------------------------------------------------------
__global__ __launch_bounds__(256) void kv_mfma(
    const float* __restrict__ wkv, const ushort_t* __restrict__ imgT,
    const float* __restrict__ bias, ushort_t* __restrict__ kvb)
{
    __shared__ ushort_t Al[128][40];   // [ch][k] f16 (pad -> 80B rows)
    __shared__ ushort_t Bl[128][40];   // [px][k] f16
    const int t = threadIdx.x;
    const int bx = blockIdx.x * 128;   // px0
    const int bm = blockIdx.y * 128;   // ch0
    const int z  = blockIdx.z;
    const int lane = t & 63, wid = t >> 6;
    const int wr = wid >> 1, wc = wid & 1;
    const int srow = t >> 1, spart = t & 1;

    f32x4 zero4 = {0.f, 0.f, 0.f, 0.f};
    f32x4 acc[4][4];
    #pragma unroll
    for (int i = 0; i < 4; ++i)
        #pragma unroll
        for (int j = 0; j < 4; ++j) acc[i][j] = zero4;

    for (int k0 = 0; k0 < 128; k0 += 32) {
        // A: wkv f32 -> f16 LDS
        const float* ap = &wkv[(size_t)(bm + srow) * 128 + k0 + spart * 16];
        float4 a0 = *(const float4*)(ap+0), a1 = *(const float4*)(ap+4);
        float4 a2 = *(const float4*)(ap+8), a3 = *(const float4*)(ap+12);
        uint4 w0, w1;
        w0.x = packrtz(a0.x,a0.y); w0.y = packrtz(a0.z,a0.w);
        w0.z = packrtz(a1.x,a1.y); w0.w = packrtz(a1.z,a1.w);
        w1.x = packrtz(a2.x,a2.y); w1.y = packrtz(a2.z,a2.w);
        w1.z = packrtz(a3.x,a3.y); w1.w = packrtz(a3.z,a3.w);
        *(uint4*)&Al[srow][spart*16]     = w0;
        *(uint4*)&Al[srow][spart*16 + 8] = w1;
        // B: imgT f16 direct
        const ushort_t* bp = &imgT[((size_t)z * NPIX + bx + srow) * 128 + k0 + spart * 16];
        *(uint4*)&Bl[srow][spart*16]     = *(const uint4*)bp;
        *(uint4*)&Bl[srow][spart*16 + 8] = *(const uint4*)(bp + 8);
        __syncthreads();
        f16x8 af[4], bf[4];
        #pragma unroll
        for (int mi = 0; mi < 4; ++mi)
            af[mi] = *(const f16x8*)&Al[wr*64 + mi*16 + (lane & 15)][(lane >> 4) * 8];
        #pragma unroll
        for (int ni = 0; ni < 4; ++ni)
            bf[ni] = *(const f16x8*)&Bl[wc*64 + ni*16 + (lane & 15)][(lane >> 4) * 8];
        #pragma unroll
        for (int mi = 0; mi < 4; ++mi)
            #pragma unroll
            for (int ni = 0; ni < 4; ++ni)
                acc[mi][ni] = __builtin_amdgcn_mfma_f32_16x16x32_f16(af[mi], bf[ni], acc[mi][ni], 0, 0, 0);
        __syncthreads();
    }

    // epilogue: D row = ch (lane>>4)*4+reg, col = px (lane&15)
    const int colp = bx + wc * 64 + (lane & 15);
    ushort_t* dstrow = kvb + ((size_t)z * NPIX + colp) * 256;
    #pragma unroll
    for (int mi = 0; mi < 4; ++mi) {
        int m0 = bm + wr * 64 + mi * 16 + (lane >> 4) * 4;   // 4 consecutive ch
        float4 bsv = *(const float4*)&bias[m0];
        int c = m0 & 127;
        int pos = ((c >> 2) << 3) + ((m0 & 128) ? 2 : 0);
        #pragma unroll
        for (int ni = 0; ni < 4; ++ni) {
            f32x4 d = acc[mi][ni];
            uint_t q0 = packrtz(d.x + bsv.x, d.y + bsv.y);
            uint_t q1 = packrtz(d.z + bsv.z, d.w + bsv.w);
            ushort_t* dd = dstrow + ni * 16 * 256 + pos;
            *(uint_t*)dd       = q0;
            *(uint_t*)(dd + 4) = q1;
        }
    }
}

// ---------------------------------------------------------------------------
// Fused BEV-side: q-proj (f16 out), offset MLP, camera projection,
// per-sample bilinear weight/address precompute. 16 px per block.
// ---------------------------------------------------------------------------
__global__ __launch_bounds__(256) void bev_mlp(
    const float* __restrict__ bev,
    const float* __restrict__ wq,    const float* __restrict__ bq,
    const float* __restrict__ woff1, const float* __restrict__ boff1,
    const float* __restrict__ woff2, const float* __restrict__ boff2,
    const float* __restrict__ Ein,   const float* __restrict__ Kin,
    const float* __restrict__ wxy,
    ushort_t* __restrict__ qb, uint4* __restrict__ sampbuf)
{
    __shared__ float bevS[128][20];   // [k][px]
    __shared__ float Ws[32][260];     // [k][out] chunk (q outs 0..127, o1 outs 128..255)
    __shared__ float o1S[128][20];    // [k][px]
    __shared__ float offS[16][16];    // [px][o]
    const int t = threadIdx.x;
    const int qg0 = blockIdx.x * 16;
    const int b   = qg0 >> 12;
    const int hw0 = qg0 & 4095;

    #pragma unroll
    for (int i = 0; i < 2; ++i) {
        int f4 = t + i * 256;                 // 0..511
        int ch = f4 >> 2, part = f4 & 3;
        float4 v = *(const float4*)&bev[((size_t)b * 128 + ch) * 4096 + hw0 + part * 4];
        *(float4*)&bevS[ch][part * 4] = v;
    }
    const float* wrow = (t < 128) ? (wq + (size_t)t * 128) : (woff1 + (size_t)(t - 128) * 128);

    const int og = t >> 2, pxg = t & 3;
    float acc[4][4] = {};
    for (int k0 = 0; k0 < 128; k0 += 32) {
        __syncthreads();
        #pragma unroll
        for (int i = 0; i < 8; ++i) {         // stage W^T chunk
            float4 wv = *(const float4*)&wrow[k0 + i * 4];
            Ws[i*4+0][t] = wv.x; Ws[i*4+1][t] = wv.y;
            Ws[i*4+2][t] = wv.z; Ws[i*4+3][t] = wv.w;
        }
        __syncthreads();
        #pragma unroll
        for (int kk = 0; kk < 32; ++kk) {
            float4 w4 = *(const float4*)&Ws[kk][og * 4];
            float4 b4 = *(const float4*)&bevS[k0 + kk][pxg * 4];
            float wa[4] = {w4.x, w4.y, w4.z, w4.w};
            float ba[4] = {b4.x, b4.y, b4.z, b4.w};
            #pragma unroll
            for (int i = 0; i < 4; ++i)
                #pragma unroll
                for (int j = 0; j < 4; ++j) acc[i][j] += wa[i] * ba[j];
        }
    }
    __syncthreads();
    if (og < 32) {                            // q epilogue -> f16 pixel-major
        int ch = og * 4;
        float4 bqv = *(const float4*)&bq[ch];
        #pragma unroll
        for (int j = 0; j < 4; ++j) {
            int px = pxg * 4 + j;
            uint_t u0 = packrtz(acc[0][j] + bqv.x, acc[1][j] + bqv.y);
            uint_t u1 = packrtz(acc[2][j] + bqv.z, acc[3][j] + bqv.w);
            *(uint2*)&qb[(size_t)(qg0 + px) * 128 + ch] = make_uint2(u0, u1);
        }
    } else {                                  // o1 -> LDS (bias + relu)
        int ch = og * 4 - 128;
        float bov[4] = {boff1[ch], boff1[ch+1], boff1[ch+2], boff1[ch+3]};
        #pragma unroll
        for (int i = 0; i < 4; ++i)
            #pragma unroll
            for (int j = 0; j < 4; ++j)
                o1S[ch + i][pxg * 4 + j] = fmaxf(acc[i][j] + bov[i], 0.f);
    }
    __syncthreads();
    {                                         // off2: thread (o, px)
        int o = t >> 4, px = t & 15;
        const float* w2 = woff2 + (size_t)o * 128;
        float s = boff2[o];
        for (int k = 0; k < 128; k += 4) {
            float4 wv = *(const float4*)&w2[k];
            s += wv.x * o1S[k][px]   + wv.y * o1S[k+1][px]
               + wv.z * o1S[k+2][px] + wv.w * o1S[k+3][px];
        }
        offS[px][o] = s;
    }
    __syncthreads();
    if (t < 96) {                             // sample-prep: (n, px)
        int n = t >> 4, px = t & 15;
        int hw = hw0 + px;
        float wx = wxy[hw], wy = wxy[4096 + hw];
        const float* e  = Ein + (size_t)(b * 6 + n) * 16;
        const float* km = Kin + (size_t)(b * 6 + n) * 9;
        float c0 = e[0]*wx + e[1]*wy + e[3];
        float c1 = e[4]*wx + e[5]*wy + e[7];
        float c2 = e[8]*wx + e[9]*wy + e[11];
        float pxx = km[0]*c0 + km[1]*c1 + km[2]*c2;
        float pyy = km[3]*c0 + km[4]*c1 + km[5]*c2;
        float pzz = fmaxf(km[6]*c0 + km[7]*c1 + km[8]*c2, 1e-6f);
        float rz = 1.f / pzz;
        float gx = pxx * rz * (2.f / 87.f) - 1.f;
        float gy = pyy * rz * (2.f / 31.f) - 1.f;
        uint4* drow = sampbuf + (size_t)(qg0 + px) * 48 + n * 8;
        #pragma unroll
        for (int p = 0; p < 8; ++p) {
            float sx = fminf(fmaxf(gx + offS[px][2*p],     -1.f), 1.f);
            float sy = fminf(fmaxf(gy + offS[px][2*p + 1], -1.f), 1.f);
            float ixf = fminf((sx + 1.f) * 43.5f, 86.99994f);   // x0 <= 86 -> x1=x0+1 safe
            float iyf = fminf((sy + 1.f) * 15.5f, 30.99998f);   // y0 <= 30
            float x0f = floorf(ixf), y0f = floorf(iyf);
            float fx = ixf - x0f, fy = iyf - y0f;
            float gxw = 1.f - fx, gyw = 1.f - fy;
            uint4 rec;
            rec.x = packrtz(gxw * gyw, fx * gyw);   // {w00, w01}
            rec.y = packrtz(gxw * fy,  fx * fy);    // {w10, w11}
            rec.z = (uint_t)((int)(y0f * 88.f + x0f) * 512);
            rec.w = 0;
            drow[p] = rec;
        }
    }
}

// ---------------------------------------------------------------------------
// Attention: wave = query. Uniform 16B sample records; 4 coalesced gathers;
// packed f16 bilinear; DPP butterfly reduce; online unnormalized softmax.
// Output channel-major f32 via LDS transpose.
// ---------------------------------------------------------------------------
__global__ __launch_bounds__(256) void attn_kernel(
    const ushort_t* __restrict__ kvb,   // [12][NPIX][256] f16 interleaved
    const ushort_t* __restrict__ qb,    // [qg][128] f16
    const uint4*    __restrict__ sampbuf, // [qg][48]
    float* __restrict__ wbuf)           // [b][128][4096]
{
    __shared__ float trS[4][130];
    const int bid = blockIdx.x;
    const int swz = (bid & 7) * 256 + (bid >> 3);   // XCD-chunked, bijective (2048%8==0)
    const int lane = threadIdx.x & 63;
    const int wv   = threadIdx.x >> 6;
    const int qg   = swz * 4 + wv;
    const int b    = qg >> 12;

    const h2 qh = u2h(((const uint_t*)qb)[(size_t)qg * 64 + lane]);
    const uint4* srow = sampbuf + (size_t)qg * 48;

    float out0 = 0.f, out1 = 0.f;
    for (int n = 0; n < NCAM; ++n) {
        const char* cb = (const char*)kvb + ((size_t)(b * 6 + n) * NPIX) * 512 + (size_t)lane * 8;
        float ssum = 0.f, vac0 = 0.f, vac1 = 0.f;
        #pragma unroll
        for (int p = 0; p < 8; ++p) {
            uint4 rec = srow[n * 8 + p];
            h2 wA = u2h(rec.x), wB = u2h(rec.y);
            const char* r0 = cb + rec.z;
            const char* r1 = r0 + IMW * 512;
            uint2 a00 = *(const uint2*)r0;
            uint2 a01 = *(const uint2*)(r0 + 512);
            uint2 a10 = *(const uint2*)r1;
            uint2 a11 = *(const uint2*)(r1 + 512);
            h2 w00 = {wA.x, wA.x}, w01 = {wA.y, wA.y};
            h2 w10 = {wB.x, wB.x}, w11 = {wB.y, wB.y};
            h2 kb = u2h(a00.x)*w00 + u2h(a01.x)*w01 + u2h(a10.x)*w10 + u2h(a11.x)*w11;
            h2 vb = u2h(a00.y)*w00 + u2h(a01.y)*w01 + u2h(a10.y)*w10 + u2h(a11.y)*w11;
#if __has_builtin(__builtin_amdgcn_fdot2)
            float s = __builtin_amdgcn_fdot2(qh, kb, 0.f, false);
#else
            float s = (float)qh.x * (float)kb.x + (float)qh.y * (float)kb.y;
#endif
            DPPADD(s, 0xB1);    // quad_perm xor1
            DPPADD(s, 0x4E);    // quad_perm xor2
            DPPADD(s, 0x141);   // row_half_mirror (xor4 after 1,2 reduced)
            DPPADD(s, 0x140);   // row_mirror      (xor8 after 1,2,4 reduced)
            float es = __expf(s);
            ssum += es;
            vac0 += es * (float)vb.x;
            vac1 += es * (float)vb.y;
        }
        float inv = 1.f / ssum;
        out0 += vac0 * inv;
        out1 += vac1 * inv;
    }
    *(float2*)&trS[wv][2 * lane] = make_float2(out0 * (1.f / NCAM), out1 * (1.f / NCAM));
    __syncthreads();
    const int t = threadIdx.x;
    if (t < 128) {
        int hw0 = (swz * 4) & 4095;
        float4 v = make_float4(trS[0][t], trS[1][t], trS[2][t], trS[3][t]);
        *(float4*)&wbuf[((size_t)b * 128 + t) * 4096 + hw0] = v;
    }
}

// ---------------------------------------------------------------------------
// Generic 64x64 SGEMM (output projection).
// ---------------------------------------------------------------------------
__global__ __launch_bounds__(256) void sgemm_kernel(
    const float* __restrict__ A, const float* __restrict__ B,
    const float* __restrict__ bias, float* __restrict__ C,
    int M, int N, int K, long strideB, long strideC)
{
    __shared__ float As[16][68];
    __shared__ float Bs[16][68];
    const float* Bb = B + (size_t)blockIdx.z * strideB;
    float*       Cb = C + (size_t)blockIdx.z * strideC;
    const int tid = threadIdx.x;
    const int bm = blockIdx.y * 64, bn = blockIdx.x * 64;
    const int tm = ((tid >> 4) & 15) << 2;
    const int tn = (tid & 15) << 2;

    float acc[4][4] = {};
    for (int k0 = 0; k0 < K; k0 += 16) {
        #pragma unroll
        for (int i = 0; i < 4; ++i) {
            int idx = tid + i * 256;
            int mk = idx >> 4, kk = idx & 15;
            As[kk][mk] = A[(size_t)(bm + mk) * K + (k0 + kk)];
        }
        #pragma unroll
        for (int i = 0; i < 4; ++i) {
            int idx = tid + i * 256;
            int kk = idx >> 6, nn = idx & 63;
            Bs[kk][nn] = Bb[(size_t)(k0 + kk) * N + (bn + nn)];
        }
        __syncthreads();
        #pragma unroll
        for (int kk = 0; kk < 16; ++kk) {
            const float4 av = *(const float4*)&As[kk][tm];
            const float4 bv = *(const float4*)&Bs[kk][tn];
            const float a[4]  = {av.x, av.y, av.z, av.w};
            const float bb[4] = {bv.x, bv.y, bv.z, bv.w};
            #pragma unroll
            for (int i = 0; i < 4; ++i)
                #pragma unroll
                for (int j = 0; j < 4; ++j) acc[i][j] += a[i] * bb[j];
        }
        __syncthreads();
    }
    #pragma unroll
    for (int i = 0; i < 4; ++i) {
        int gm = bm + tm + i;
        float bi = bias[gm];
        float4 v = make_float4(acc[i][0]+bi, acc[i][1]+bi, acc[i][2]+bi, acc[i][3]+bi);
        *(float4*)&Cb[(size_t)gm * N + (bn + tn)] = v;
    }
}

// ---------------------------------------------------------------------------
extern "C" void kernel_launch(void* const* d_in, const int* in_sizes, int n_in,
                              void* d_out, int out_size, void* d_ws, size_t ws_size,
                              hipStream_t stream)
{
    const float* bev   = (const float*)d_in[0];
    const float* img   = (const float*)d_in[1];
    const float* Kin   = (const float*)d_in[2];
    const float* Ein   = (const float*)d_in[3];
    const float* wxy   = (const float*)d_in[4];
    const float* wq    = (const float*)d_in[5];
    const float* bq    = (const float*)d_in[6];
    const float* wkv   = (const float*)d_in[7];
    const float* bkv   = (const float*)d_in[8];
    const float* woff1 = (const float*)d_in[9];
    const float* boff1 = (const float*)d_in[10];
    const float* woff2 = (const float*)d_in[11];
    const float* boff2 = (const float*)d_in[12];
    const float* wproj = (const float*)d_in[13];
    const float* bproj = (const float*)d_in[14];
    float* out = (float*)d_out;

    char* wsb = (char*)d_ws;
    ushort_t* kvb   = (ushort_t*)wsb;                       // 17,301,504 B
    ushort_t* imgTb = (ushort_t*)(wsb + 17301504);          //  8,650,752 B
    ushort_t* qbb   = (ushort_t*)(wsb + 25952256);          //  2,097,152 B
    uint4*    sampb = (uint4*)   (wsb + 28049408);          //  6,291,456 B
    float*    wbuf  = (float*)   (wsb + 34340864);          //  4,194,304 B

    imgT_kernel<<<dim3(NPIX/64, 12), 256, 0, stream>>>(img, imgTb);
    bev_mlp<<<dim3(2*HWQ/16), 256, 0, stream>>>(
        bev, wq, bq, woff1, boff1, woff2, boff2, Ein, Kin, wxy, qbb, sampb);
    kv_mfma<<<dim3(NPIX/128, 2, 12), 256, 0, stream>>>(wkv, imgTb, bkv, kvb);
    attn_kernel<<<dim3(2*HWQ/4), 256, 0, stream>>>(kvb, qbb, sampb, wbuf);
    sgemm_kernel<<<dim3(HWQ/64, 2, 2), 256, 0, stream>>>(
        wproj, wbuf, bproj, out, 128, HWQ, 128, (long)128*HWQ, (long)128*HWQ);
}

// Round 6
// 118.368 us; speedup vs baseline: 2.7595x; 1.0762x over previous
//
#include <hip/hip_runtime.h>

#define HWQ  4096      // H*W = 64*64
#define NCAM 6
#define IMH  32
#define IMW  88
#define NPIX (IMH*IMW) // 2816

typedef unsigned short ushort_t;
typedef unsigned int   uint_t;
typedef __fp16 h2   __attribute__((ext_vector_type(2)));
typedef __fp16 f16x8 __attribute__((ext_vector_type(8)));
typedef float  f32x4 __attribute__((ext_vector_type(4)));

union UH { uint_t u; h2 h; };
__device__ inline h2 u2h(uint_t x){ UH c; c.u = x; return c.h; }
__device__ inline uint_t packrtz(float a, float b){
    UH c; c.h = __builtin_amdgcn_cvt_pkrtz(a, b); return c.u;
}

// butterfly add within 16-lane rows, VALU-only (DPP)
#define DPPADD(s, ctrl) { \
    int _x = __builtin_amdgcn_update_dpp(0, __float_as_int(s), ctrl, 0xF, 0xF, true); \
    s += __int_as_float(_x); }

// ---------------------------------------------------------------------------
// img [z][128ch][2816px] f32  ->  imgT [z][2816px][128ch] f16
// ---------------------------------------------------------------------------
__global__ __launch_bounds__(256) void imgT_kernel(
    const float* __restrict__ img, ushort_t* __restrict__ imgT)
{
    __shared__ ushort_t T[64][136];          // [px][ch], pad 8
    const int t = threadIdx.x;
    const int z = blockIdx.y;
    const int px0 = blockIdx.x * 64;
    const float* src = img + (size_t)z * 128 * NPIX;
    #pragma unroll
    for (int i = 0; i < 8; ++i) {
        int f4 = t + i * 256;                // 0..2047
        int ch = f4 >> 4, part = f4 & 15;
        float4 v = *(const float4*)&src[(size_t)ch * NPIX + px0 + part * 4];
        uint_t p01 = packrtz(v.x, v.y), p23 = packrtz(v.z, v.w);
        T[part*4+0][ch] = (ushort_t)p01;
        T[part*4+1][ch] = (ushort_t)(p01 >> 16);
        T[part*4+2][ch] = (ushort_t)p23;
        T[part*4+3][ch] = (ushort_t)(p23 >> 16);
    }
    __syncthreads();
    #pragma unroll
    for (int i = 0; i < 4; ++i) {
        int idx = t + i * 256;               // 0..1023
        int px = idx >> 4, c8 = (idx & 15) * 8;
        *(uint4*)&imgT[((size_t)z * NPIX + px0 + px) * 128 + c8] = *(const uint4*)&T[px][c8];
    }
}

// ---------------------------------------------------------------------------
// KV 1x1 conv via f16 MFMA: C[256ch][2816px] = wkv @ imgT^T, per z.
// Output f16 channel-interleaved pixel rows: u16[256] = [K0,K1,V0,V1,K2,K3,V2,V3,..]
// ---------------------------------------------------------------------------
__global__ __launch_bounds__(256) void kv_mfma(
    const float* __restrict__ wkv, const ushort_t* __restrict__ imgT,
    const float* __restrict__ bias, ushort_t* __restrict__ kvb)
{
    __shared__ ushort_t Al[128][40];   // [ch][k] f16 (pad -> 80B rows)
    __shared__ ushort_t Bl[128][40];   // [px][k] f16
    const int t = threadIdx.x;
    const int bx = blockIdx.x * 128;   // px0
    const int bm = blockIdx.y * 128;   // ch0
    const int z  = blockIdx.z;
    const int lane = t & 63, wid = t >> 6;
    const int wr = wid >> 1, wc = wid & 1;
    const int srow = t >> 1, spart = t & 1;

    f32x4 zero4 = {0.f, 0.f, 0.f, 0.f};
    f32x4 acc[4][4];
    #pragma unroll
    for (int i = 0; i < 4; ++i)
        #pragma unroll
        for (int j = 0; j < 4; ++j) acc[i][j] = zero4;

    for (int k0 = 0; k0 < 128; k0 += 32) {
        // A: wkv f32 -> f16 LDS
        const float* ap = &wkv[(size_t)(bm + srow) * 128 + k0 + spart * 16];
        float4 a0 = *(const float4*)(ap+0), a1 = *(const float4*)(ap+4);
        float4 a2 = *(const float4*)(ap+8), a3 = *(const float4*)(ap+12);
        uint4 w0, w1;
        w0.x = packrtz(a0.x,a0.y); w0.y = packrtz(a0.z,a0.w);
        w0.z = packrtz(a1.x,a1.y); w0.w = packrtz(a1.z,a1.w);
        w1.x = packrtz(a2.x,a2.y); w1.y = packrtz(a2.z,a2.w);
        w1.z = packrtz(a3.x,a3.y); w1.w = packrtz(a3.z,a3.w);
        *(uint4*)&Al[srow][spart*16]     = w0;
        *(uint4*)&Al[srow][spart*16 + 8] = w1;
        // B: imgT f16 direct
        const ushort_t* bp = &imgT[((size_t)z * NPIX + bx + srow) * 128 + k0 + spart * 16];
        *(uint4*)&Bl[srow][spart*16]     = *(const uint4*)bp;
        *(uint4*)&Bl[srow][spart*16 + 8] = *(const uint4*)(bp + 8);
        __syncthreads();
        f16x8 af[4], bf[4];
        #pragma unroll
        for (int mi = 0; mi < 4; ++mi)
            af[mi] = *(const f16x8*)&Al[wr*64 + mi*16 + (lane & 15)][(lane >> 4) * 8];
        #pragma unroll
        for (int ni = 0; ni < 4; ++ni)
            bf[ni] = *(const f16x8*)&Bl[wc*64 + ni*16 + (lane & 15)][(lane >> 4) * 8];
        #pragma unroll
        for (int mi = 0; mi < 4; ++mi)
            #pragma unroll
            for (int ni = 0; ni < 4; ++ni)
                acc[mi][ni] = __builtin_amdgcn_mfma_f32_16x16x32_f16(af[mi], bf[ni], acc[mi][ni], 0, 0, 0);
        __syncthreads();
    }

    // epilogue: D row = ch (lane>>4)*4+reg, col = px (lane&15)
    const int colp = bx + wc * 64 + (lane & 15);
    ushort_t* dstrow = kvb + ((size_t)z * NPIX + colp) * 256;
    #pragma unroll
    for (int mi = 0; mi < 4; ++mi) {
        int m0 = bm + wr * 64 + mi * 16 + (lane >> 4) * 4;   // 4 consecutive ch
        float4 bsv = *(const float4*)&bias[m0];
        int c = m0 & 127;
        int pos = ((c >> 2) << 3) + ((m0 & 128) ? 2 : 0);
        #pragma unroll
        for (int ni = 0; ni < 4; ++ni) {
            f32x4 d = acc[mi][ni];
            uint_t q0 = packrtz(d.x + bsv.x, d.y + bsv.y);
            uint_t q1 = packrtz(d.z + bsv.z, d.w + bsv.w);
            ushort_t* dd = dstrow + ni * 16 * 256 + pos;
            *(uint_t*)dd       = q0;
            *(uint_t*)(dd + 4) = q1;
        }
    }
}

// ---------------------------------------------------------------------------
// Fused BEV-side: q-proj (f16 out), offset MLP, camera projection,
// per-sample bilinear weight/address precompute. 16 px per block.
// ---------------------------------------------------------------------------
__global__ __launch_bounds__(256) void bev_mlp(
    const float* __restrict__ bev,
    const float* __restrict__ wq,    const float* __restrict__ bq,
    const float* __restrict__ woff1, const float* __restrict__ boff1,
    const float* __restrict__ woff2, const float* __restrict__ boff2,
    const float* __restrict__ Ein,   const float* __restrict__ Kin,
    const float* __restrict__ wxy,
    ushort_t* __restrict__ qb, uint4* __restrict__ sampbuf)
{
    __shared__ float bevS[128][20];   // [k][px]
    __shared__ float Ws[32][260];     // [k][out] chunk (q outs 0..127, o1 outs 128..255)
    __shared__ float o1S[128][20];    // [k][px]
    __shared__ float offS[16][16];    // [px][o]
    const int t = threadIdx.x;
    const int qg0 = blockIdx.x * 16;
    const int b   = qg0 >> 12;
    const int hw0 = qg0 & 4095;

    #pragma unroll
    for (int i = 0; i < 2; ++i) {
        int f4 = t + i * 256;                 // 0..511
        int ch = f4 >> 2, part = f4 & 3;
        float4 v = *(const float4*)&bev[((size_t)b * 128 + ch) * 4096 + hw0 + part * 4];
        *(float4*)&bevS[ch][part * 4] = v;
    }
    const float* wrow = (t < 128) ? (wq + (size_t)t * 128) : (woff1 + (size_t)(t - 128) * 128);

    const int og = t >> 2, pxg = t & 3;
    float acc[4][4] = {};
    for (int k0 = 0; k0 < 128; k0 += 32) {
        __syncthreads();
        #pragma unroll
        for (int i = 0; i < 8; ++i) {         // stage W^T chunk
            float4 wv = *(const float4*)&wrow[k0 + i * 4];
            Ws[i*4+0][t] = wv.x; Ws[i*4+1][t] = wv.y;
            Ws[i*4+2][t] = wv.z; Ws[i*4+3][t] = wv.w;
        }
        __syncthreads();
        #pragma unroll
        for (int kk = 0; kk < 32; ++kk) {
            float4 w4 = *(const float4*)&Ws[kk][og * 4];
            float4 b4 = *(const float4*)&bevS[k0 + kk][pxg * 4];
            float wa[4] = {w4.x, w4.y, w4.z, w4.w};
            float ba[4] = {b4.x, b4.y, b4.z, b4.w};
            #pragma unroll
            for (int i = 0; i < 4; ++i)
                #pragma unroll
                for (int j = 0; j < 4; ++j) acc[i][j] += wa[i] * ba[j];
        }
    }
    __syncthreads();
    if (og < 32) {                            // q epilogue -> f16 pixel-major
        int ch = og * 4;
        float4 bqv = *(const float4*)&bq[ch];
        #pragma unroll
        for (int j = 0; j < 4; ++j) {
            int px = pxg * 4 + j;
            uint_t u0 = packrtz(acc[0][j] + bqv.x, acc[1][j] + bqv.y);
            uint_t u1 = packrtz(acc[2][j] + bqv.z, acc[3][j] + bqv.w);
            *(uint2*)&qb[(size_t)(qg0 + px) * 128 + ch] = make_uint2(u0, u1);
        }
    } else {                                  // o1 -> LDS (bias + relu)
        int ch = og * 4 - 128;
        float bov[4] = {boff1[ch], boff1[ch+1], boff1[ch+2], boff1[ch+3]};
        #pragma unroll
        for (int i = 0; i < 4; ++i)
            #pragma unroll
            for (int j = 0; j < 4; ++j)
                o1S[ch + i][pxg * 4 + j] = fmaxf(acc[i][j] + bov[i], 0.f);
    }
    __syncthreads();
    {                                         // off2: thread (o, px)
        int o = t >> 4, px = t & 15;
        const float* w2 = woff2 + (size_t)o * 128;
        float s = boff2[o];
        for (int k = 0; k < 128; k += 4) {
            float4 wv = *(const float4*)&w2[k];
            s += wv.x * o1S[k][px]   + wv.y * o1S[k+1][px]
               + wv.z * o1S[k+2][px] + wv.w * o1S[k+3][px];
        }
        offS[px][o] = s;
    }
    __syncthreads();
    if (t < 96) {                             // sample-prep: (n, px)
        int n = t >> 4, px = t & 15;
        int hw = hw0 + px;
        float wx = wxy[hw], wy = wxy[4096 + hw];
        const float* e  = Ein + (size_t)(b * 6 + n) * 16;
        const float* km = Kin + (size_t)(b * 6 + n) * 9;
        float c0 = e[0]*wx + e[1]*wy + e[3];
        float c1 = e[4]*wx + e[5]*wy + e[7];
        float c2 = e[8]*wx + e[9]*wy + e[11];
        float pxx = km[0]*c0 + km[1]*c1 + km[2]*c2;
        float pyy = km[3]*c0 + km[4]*c1 + km[5]*c2;
        float pzz = fmaxf(km[6]*c0 + km[7]*c1 + km[8]*c2, 1e-6f);
        float rz = 1.f / pzz;
        float gx = pxx * rz * (2.f / 87.f) - 1.f;
        float gy = pyy * rz * (2.f / 31.f) - 1.f;
        uint4* drow = sampbuf + (size_t)(qg0 + px) * 48 + n * 8;
        #pragma unroll
        for (int p = 0; p < 8; ++p) {
            float sx = fminf(fmaxf(gx + offS[px][2*p],     -1.f), 1.f);
            float sy = fminf(fmaxf(gy + offS[px][2*p + 1], -1.f), 1.f);
            float ixf = fminf((sx + 1.f) * 43.5f, 86.99994f);   // x0 <= 86 -> x1=x0+1 safe
            float iyf = fminf((sy + 1.f) * 15.5f, 30.99998f);   // y0 <= 30
            float x0f = floorf(ixf), y0f = floorf(iyf);
            float fx = ixf - x0f, fy = iyf - y0f;
            float gxw = 1.f - fx, gyw = 1.f - fy;
            uint4 rec;
            rec.x = packrtz(gxw * gyw, fx * gyw);   // {w00, w01}
            rec.y = packrtz(gxw * fy,  fx * fy);    // {w10, w11}
            rec.z = (uint_t)((int)(y0f * 88.f + x0f) * 512);
            rec.w = 0;
            drow[p] = rec;
        }
    }
}

// ---------------------------------------------------------------------------
// Attention: 512 threads = 8 waves = 4 queries x 2 camera-halves.
// Sample records staged in LDS (wave-uniform ds_read broadcast).
// Packed f16 bilinear; DPP butterfly reduce; unnormalized online softmax.
// Cross-half combine + channel-major f32 output via LDS transpose.
// ---------------------------------------------------------------------------
__global__ __launch_bounds__(512) void attn_kernel(
    const ushort_t* __restrict__ kvb,     // [12][NPIX][256] f16 interleaved
    const ushort_t* __restrict__ qb,      // [qg][128] f16
    const uint4*    __restrict__ sampbuf, // [qg][48]
    float* __restrict__ wbuf)             // [b][128][4096]
{
    __shared__ uint4 recS[192];           // 4 queries x 48 recs
    __shared__ float trS[8][132];
    const int bid = blockIdx.x;
    const int swz = (bid & 7) * 256 + (bid >> 3);   // XCD-chunked, bijective (2048%8==0)
    const int t    = threadIdx.x;
    const int lane = t & 63;
    const int w    = t >> 6;              // 0..7
    const int ql   = w >> 1;              // query within block
    const int c0   = (w & 1) * 3;         // first camera of this half
    const int qg0  = swz * 4;
    const int qg   = qg0 + ql;
    const int b    = qg >> 12;

    if (t < 192) recS[t] = sampbuf[(size_t)qg0 * 48 + t];
    const h2 qh = u2h(((const uint_t*)qb)[(size_t)qg * 64 + lane]);
    __syncthreads();

    float out0 = 0.f, out1 = 0.f;
    #pragma unroll
    for (int i = 0; i < 3; ++i) {
        const int n = c0 + i;
        const char* cb = (const char*)kvb + ((size_t)(b * 6 + n) * NPIX) * 512 + (size_t)lane * 8;
        const uint4* rrow = &recS[ql * 48 + n * 8];
        float ssum = 0.f, vac0 = 0.f, vac1 = 0.f;
        #pragma unroll
        for (int p = 0; p < 8; ++p) {
            uint4 rec = rrow[p];
            h2 wA = u2h(rec.x), wB = u2h(rec.y);
            const char* r0 = cb + rec.z;
            const char* r1 = r0 + IMW * 512;
            uint2 a00 = *(const uint2*)r0;
            uint2 a01 = *(const uint2*)(r0 + 512);
            uint2 a10 = *(const uint2*)r1;
            uint2 a11 = *(const uint2*)(r1 + 512);
            h2 w00 = {wA.x, wA.x}, w01 = {wA.y, wA.y};
            h2 w10 = {wB.x, wB.x}, w11 = {wB.y, wB.y};
            h2 kb = u2h(a00.x)*w00 + u2h(a01.x)*w01 + u2h(a10.x)*w10 + u2h(a11.x)*w11;
            h2 vb = u2h(a00.y)*w00 + u2h(a01.y)*w01 + u2h(a10.y)*w10 + u2h(a11.y)*w11;
#if __has_builtin(__builtin_amdgcn_fdot2)
            float s = __builtin_amdgcn_fdot2(qh, kb, 0.f, false);
#else
            float s = (float)qh.x * (float)kb.x + (float)qh.y * (float)kb.y;
#endif
            DPPADD(s, 0xB1);    // quad_perm xor1
            DPPADD(s, 0x4E);    // quad_perm xor2
            DPPADD(s, 0x141);   // row_half_mirror (xor4)
            DPPADD(s, 0x140);   // row_mirror      (xor8)
            float es = __expf(s);
            ssum += es;
            vac0 += es * (float)vb.x;
            vac1 += es * (float)vb.y;
        }
        float inv = 1.f / ssum;
        out0 += vac0 * inv;
        out1 += vac1 * inv;
    }
    *(float2*)&trS[w][2 * lane] = make_float2(out0 * (1.f / NCAM), out1 * (1.f / NCAM));
    __syncthreads();
    if (t < 128) {
        int hw0 = qg0 & 4095;
        float4 v = make_float4(trS[0][t] + trS[1][t], trS[2][t] + trS[3][t],
                               trS[4][t] + trS[5][t], trS[6][t] + trS[7][t]);
        *(float4*)&wbuf[((size_t)(qg0 >> 12) * 128 + t) * 4096 + hw0] = v;
    }
}

// ---------------------------------------------------------------------------
// Generic 64x64 SGEMM (output projection).
// ---------------------------------------------------------------------------
__global__ __launch_bounds__(256) void sgemm_kernel(
    const float* __restrict__ A, const float* __restrict__ B,
    const float* __restrict__ bias, float* __restrict__ C,
    int M, int N, int K, long strideB, long strideC)
{
    __shared__ float As[16][68];
    __shared__ float Bs[16][68];
    const float* Bb = B + (size_t)blockIdx.z * strideB;
    float*       Cb = C + (size_t)blockIdx.z * strideC;
    const int tid = threadIdx.x;
    const int bm = blockIdx.y * 64, bn = blockIdx.x * 64;
    const int tm = ((tid >> 4) & 15) << 2;
    const int tn = (tid & 15) << 2;

    float acc[4][4] = {};
    for (int k0 = 0; k0 < K; k0 += 16) {
        #pragma unroll
        for (int i = 0; i < 4; ++i) {
            int idx = tid + i * 256;
            int mk = idx >> 4, kk = idx & 15;
            As[kk][mk] = A[(size_t)(bm + mk) * K + (k0 + kk)];
        }
        #pragma unroll
        for (int i = 0; i < 4; ++i) {
            int idx = tid + i * 256;
            int kk = idx >> 6, nn = idx & 63;
            Bs[kk][nn] = Bb[(size_t)(k0 + kk) * N + (bn + nn)];
        }
        __syncthreads();
        #pragma unroll
        for (int kk = 0; kk < 16; ++kk) {
            const float4 av = *(const float4*)&As[kk][tm];
            const float4 bv = *(const float4*)&Bs[kk][tn];
            const float a[4]  = {av.x, av.y, av.z, av.w};
            const float bb[4] = {bv.x, bv.y, bv.z, bv.w};
            #pragma unroll
            for (int i = 0; i < 4; ++i)
                #pragma unroll
                for (int j = 0; j < 4; ++j) acc[i][j] += a[i] * bb[j];
        }
        __syncthreads();
    }
    #pragma unroll
    for (int i = 0; i < 4; ++i) {
        int gm = bm + tm + i;
        float bi = bias[gm];
        float4 v = make_float4(acc[i][0]+bi, acc[i][1]+bi, acc[i][2]+bi, acc[i][3]+bi);
        *(float4*)&Cb[(size_t)gm * N + (bn + tn)] = v;
    }
}

// ---------------------------------------------------------------------------
extern "C" void kernel_launch(void* const* d_in, const int* in_sizes, int n_in,
                              void* d_out, int out_size, void* d_ws, size_t ws_size,
                              hipStream_t stream)
{
    const float* bev   = (const float*)d_in[0];
    const float* img   = (const float*)d_in[1];
    const float* Kin   = (const float*)d_in[2];
    const float* Ein   = (const float*)d_in[3];
    const float* wxy   = (const float*)d_in[4];
    const float* wq    = (const float*)d_in[5];
    const float* bq    = (const float*)d_in[6];
    const float* wkv   = (const float*)d_in[7];
    const float* bkv   = (const float*)d_in[8];
    const float* woff1 = (const float*)d_in[9];
    const float* boff1 = (const float*)d_in[10];
    const float* woff2 = (const float*)d_in[11];
    const float* boff2 = (const float*)d_in[12];
    const float* wproj = (const float*)d_in[13];
    const float* bproj = (const float*)d_in[14];
    float* out = (float*)d_out;

    char* wsb = (char*)d_ws;
    ushort_t* kvb   = (ushort_t*)wsb;                       // 17,301,504 B
    ushort_t* imgTb = (ushort_t*)(wsb + 17301504);          //  8,650,752 B
    ushort_t* qbb   = (ushort_t*)(wsb + 25952256);          //  2,097,152 B
    uint4*    sampb = (uint4*)   (wsb + 28049408);          //  6,291,456 B
    float*    wbuf  = (float*)   (wsb + 34340864);          //  4,194,304 B

    imgT_kernel<<<dim3(NPIX/64, 12), 256, 0, stream>>>(img, imgTb);
    bev_mlp<<<dim3(2*HWQ/16), 256, 0, stream>>>(
        bev, wq, bq, woff1, boff1, woff2, boff2, Ein, Kin, wxy, qbb, sampb);
    kv_mfma<<<dim3(NPIX/128, 2, 12), 256, 0, stream>>>(wkv, imgTb, bkv, kvb);
    attn_kernel<<<dim3(2*HWQ/4), 512, 0, stream>>>(kvb, qbb, sampb, wbuf);
    sgemm_kernel<<<dim3(HWQ/64, 2, 2), 256, 0, stream>>>(
        wproj, wbuf, bproj, out, 128, HWQ, 128, (long)128*HWQ, (long)128*HWQ);
}

// Round 7
// 108.901 us; speedup vs baseline: 2.9994x; 1.0869x over previous
//
#include <hip/hip_runtime.h>

#define HWQ  4096      // H*W = 64*64
#define NCAM 6
#define IMH  32
#define IMW  88
#define NPIX (IMH*IMW) // 2816

typedef unsigned short ushort_t;
typedef unsigned int   uint_t;
typedef __fp16 h2   __attribute__((ext_vector_type(2)));
typedef __fp16 f16x8 __attribute__((ext_vector_type(8)));
typedef float  f32x4 __attribute__((ext_vector_type(4)));

union UH { uint_t u; h2 h; };
__device__ inline h2 u2h(uint_t x){ UH c; c.u = x; return c.h; }
__device__ inline uint_t packrtz(float a, float b){
    UH c; c.h = __builtin_amdgcn_cvt_pkrtz(a, b); return c.u;
}

// butterfly add within 16-lane rows, VALU-only (DPP)
#define DPPADD(s, ctrl) { \
    int _x = __builtin_amdgcn_update_dpp(0, __float_as_int(s), ctrl, 0xF, 0xF, true); \
    s += __int_as_float(_x); }

// ---------------------------------------------------------------------------
// img [z][128ch][2816px] f32  ->  imgT [z][2816px][128ch] f16
// ---------------------------------------------------------------------------
__global__ __launch_bounds__(256) void imgT_kernel(
    const float* __restrict__ img, ushort_t* __restrict__ imgT)
{
    __shared__ ushort_t T[64][136];          // [px][ch], pad 8
    const int t = threadIdx.x;
    const int z = blockIdx.y;
    const int px0 = blockIdx.x * 64;
    const float* src = img + (size_t)z * 128 * NPIX;
    #pragma unroll
    for (int i = 0; i < 8; ++i) {
        int f4 = t + i * 256;                // 0..2047
        int ch = f4 >> 4, part = f4 & 15;
        float4 v = *(const float4*)&src[(size_t)ch * NPIX + px0 + part * 4];
        uint_t p01 = packrtz(v.x, v.y), p23 = packrtz(v.z, v.w);
        T[part*4+0][ch] = (ushort_t)p01;
        T[part*4+1][ch] = (ushort_t)(p01 >> 16);
        T[part*4+2][ch] = (ushort_t)p23;
        T[part*4+3][ch] = (ushort_t)(p23 >> 16);
    }
    __syncthreads();
    #pragma unroll
    for (int i = 0; i < 4; ++i) {
        int idx = t + i * 256;               // 0..1023
        int px = idx >> 4, c8 = (idx & 15) * 8;
        *(uint4*)&imgT[((size_t)z * NPIX + px0 + px) * 128 + c8] = *(const uint4*)&T[px][c8];
    }
}

// ---------------------------------------------------------------------------
// KV 1x1 conv via f16 MFMA. Block = (128 px) x (64 K-ch + 64 V-ch of half y).
// Tile rows 0..63 = wkv rows y*64+r (K); rows 64..127 = wkv rows 128+y*64+(r-64) (V).
// Epilogue stages interleaved pixel rows in LDS, stores coalesced uint4.
// Row layout (u16): [k2j,k2j+1,v2j,v2j+1] at 4j  (j = half-relative pair idx).
// ---------------------------------------------------------------------------
__global__ __launch_bounds__(256) void kv_mfma(
    const float* __restrict__ wkv, const ushort_t* __restrict__ imgT,
    const float* __restrict__ bias, ushort_t* __restrict__ kvb)
{
    __shared__ ushort_t Al[128][40];    // [tile-row][k] f16
    __shared__ ushort_t Bl[128][40];    // [px][k] f16
    __shared__ ushort_t St[128][140];   // [px][region u16], pad->2-way banks
    const int t = threadIdx.x;
    const int bx = blockIdx.x * 128;    // px0
    const int y  = blockIdx.y;          // ch half
    const int z  = blockIdx.z;
    const int lane = t & 63, wid = t >> 6;
    const int wr = wid >> 1, wc = wid & 1;
    const int srow = t >> 1, spart = t & 1;
    const int grA = (srow < 64) ? (y * 64 + srow) : (64 + y * 64 + srow);

    f32x4 zero4 = {0.f, 0.f, 0.f, 0.f};
    f32x4 acc[4][4];
    #pragma unroll
    for (int i = 0; i < 4; ++i)
        #pragma unroll
        for (int j = 0; j < 4; ++j) acc[i][j] = zero4;

    for (int k0 = 0; k0 < 128; k0 += 32) {
        // A: wkv f32 -> f16 LDS
        const float* ap = &wkv[(size_t)grA * 128 + k0 + spart * 16];
        float4 a0 = *(const float4*)(ap+0), a1 = *(const float4*)(ap+4);
        float4 a2 = *(const float4*)(ap+8), a3 = *(const float4*)(ap+12);
        uint4 w0, w1;
        w0.x = packrtz(a0.x,a0.y); w0.y = packrtz(a0.z,a0.w);
        w0.z = packrtz(a1.x,a1.y); w0.w = packrtz(a1.z,a1.w);
        w1.x = packrtz(a2.x,a2.y); w1.y = packrtz(a2.z,a2.w);
        w1.z = packrtz(a3.x,a3.y); w1.w = packrtz(a3.z,a3.w);
        *(uint4*)&Al[srow][spart*16]     = w0;
        *(uint4*)&Al[srow][spart*16 + 8] = w1;
        // B: imgT f16 direct
        const ushort_t* bp = &imgT[((size_t)z * NPIX + bx + srow) * 128 + k0 + spart * 16];
        *(uint4*)&Bl[srow][spart*16]     = *(const uint4*)bp;
        *(uint4*)&Bl[srow][spart*16 + 8] = *(const uint4*)(bp + 8);
        __syncthreads();
        f16x8 af[4], bf[4];
        #pragma unroll
        for (int mi = 0; mi < 4; ++mi)
            af[mi] = *(const f16x8*)&Al[wr*64 + mi*16 + (lane & 15)][(lane >> 4) * 8];
        #pragma unroll
        for (int ni = 0; ni < 4; ++ni)
            bf[ni] = *(const f16x8*)&Bl[wc*64 + ni*16 + (lane & 15)][(lane >> 4) * 8];
        #pragma unroll
        for (int mi = 0; mi < 4; ++mi)
            #pragma unroll
            for (int ni = 0; ni < 4; ++ni)
                acc[mi][ni] = __builtin_amdgcn_mfma_f32_16x16x32_f16(af[mi], bf[ni], acc[mi][ni], 0, 0, 0);
        __syncthreads();
    }

    // ---- epilogue: LDS stage (interleaved layout), then coalesced store ----
    #pragma unroll
    for (int mi = 0; mi < 4; ++mi) {
        int m0  = wr * 64 + mi * 16 + (lane >> 4) * 4;   // tile row (4 consecutive)
        int gm0 = (m0 < 64) ? (y * 64 + m0) : (64 + y * 64 + m0);
        float4 bsv = *(const float4*)&bias[gm0];
        int off0 = (m0 < 64) ? (2 * m0) : (2 * (m0 - 64) + 2);
        #pragma unroll
        for (int ni = 0; ni < 4; ++ni) {
            int pxl = wc * 64 + ni * 16 + (lane & 15);
            f32x4 d = acc[mi][ni];
            *(uint_t*)&St[pxl][off0]     = packrtz(d.x + bsv.x, d.y + bsv.y);
            *(uint_t*)&St[pxl][off0 + 4] = packrtz(d.z + bsv.z, d.w + bsv.w);
        }
    }
    __syncthreads();
    #pragma unroll
    for (int it = 0; it < 8; ++it) {
        int idx = t + it * 256;              // 0..2047
        int px = idx >> 4, c16 = idx & 15;
        uint4 v = *(const uint4*)&St[px][c16 * 8];
        *(uint4*)&kvb[((size_t)z * NPIX + bx + px) * 256 + y * 128 + c16 * 8] = v;
    }
}

// ---------------------------------------------------------------------------
// Fused BEV-side: q-proj (f16 out), offset MLP, camera projection,
// per-sample bilinear weight/address precompute. 16 px per block.
// ---------------------------------------------------------------------------
__global__ __launch_bounds__(256) void bev_mlp(
    const float* __restrict__ bev,
    const float* __restrict__ wq,    const float* __restrict__ bq,
    const float* __restrict__ woff1, const float* __restrict__ boff1,
    const float* __restrict__ woff2, const float* __restrict__ boff2,
    const float* __restrict__ Ein,   const float* __restrict__ Kin,
    const float* __restrict__ wxy,
    ushort_t* __restrict__ qb, uint4* __restrict__ sampbuf)
{
    __shared__ float bevS[128][20];   // [k][px]
    __shared__ float Ws[32][260];     // [k][out] chunk (q outs 0..127, o1 outs 128..255)
    __shared__ float o1S[128][20];    // [k][px]
    __shared__ float offS[16][16];    // [px][o]
    const int t = threadIdx.x;
    const int qg0 = blockIdx.x * 16;
    const int b   = qg0 >> 12;
    const int hw0 = qg0 & 4095;

    #pragma unroll
    for (int i = 0; i < 2; ++i) {
        int f4 = t + i * 256;                 // 0..511
        int ch = f4 >> 2, part = f4 & 3;
        float4 v = *(const float4*)&bev[((size_t)b * 128 + ch) * 4096 + hw0 + part * 4];
        *(float4*)&bevS[ch][part * 4] = v;
    }
    const float* wrow = (t < 128) ? (wq + (size_t)t * 128) : (woff1 + (size_t)(t - 128) * 128);

    const int og = t >> 2, pxg = t & 3;
    float acc[4][4] = {};
    for (int k0 = 0; k0 < 128; k0 += 32) {
        __syncthreads();
        #pragma unroll
        for (int i = 0; i < 8; ++i) {         // stage W^T chunk
            float4 wv = *(const float4*)&wrow[k0 + i * 4];
            Ws[i*4+0][t] = wv.x; Ws[i*4+1][t] = wv.y;
            Ws[i*4+2][t] = wv.z; Ws[i*4+3][t] = wv.w;
        }
        __syncthreads();
        #pragma unroll
        for (int kk = 0; kk < 32; ++kk) {
            float4 w4 = *(const float4*)&Ws[kk][og * 4];
            float4 b4 = *(const float4*)&bevS[k0 + kk][pxg * 4];
            float wa[4] = {w4.x, w4.y, w4.z, w4.w};
            float ba[4] = {b4.x, b4.y, b4.z, b4.w};
            #pragma unroll
            for (int i = 0; i < 4; ++i)
                #pragma unroll
                for (int j = 0; j < 4; ++j) acc[i][j] += wa[i] * ba[j];
        }
    }
    __syncthreads();
    if (og < 32) {                            // q epilogue -> f16 pixel-major
        int ch = og * 4;
        float4 bqv = *(const float4*)&bq[ch];
        #pragma unroll
        for (int j = 0; j < 4; ++j) {
            int px = pxg * 4 + j;
            uint_t u0 = packrtz(acc[0][j] + bqv.x, acc[1][j] + bqv.y);
            uint_t u1 = packrtz(acc[2][j] + bqv.z, acc[3][j] + bqv.w);
            *(uint2*)&qb[(size_t)(qg0 + px) * 128 + ch] = make_uint2(u0, u1);
        }
    } else {                                  // o1 -> LDS (bias + relu)
        int ch = og * 4 - 128;
        float bov[4] = {boff1[ch], boff1[ch+1], boff1[ch+2], boff1[ch+3]};
        #pragma unroll
        for (int i = 0; i < 4; ++i)
            #pragma unroll
            for (int j = 0; j < 4; ++j)
                o1S[ch + i][pxg * 4 + j] = fmaxf(acc[i][j] + bov[i], 0.f);
    }
    __syncthreads();
    {                                         // off2: thread (o, px)
        int o = t >> 4, px = t & 15;
        const float* w2 = woff2 + (size_t)o * 128;
        float s = boff2[o];
        for (int k = 0; k < 128; k += 4) {
            float4 wv = *(const float4*)&w2[k];
            s += wv.x * o1S[k][px]   + wv.y * o1S[k+1][px]
               + wv.z * o1S[k+2][px] + wv.w * o1S[k+3][px];
        }
        offS[px][o] = s;
    }
    __syncthreads();
    if (t < 96) {                             // sample-prep: (n, px)
        int n = t >> 4, px = t & 15;
        int hw = hw0 + px;
        float wx = wxy[hw], wy = wxy[4096 + hw];
        const float* e  = Ein + (size_t)(b * 6 + n) * 16;
        const float* km = Kin + (size_t)(b * 6 + n) * 9;
        float c0 = e[0]*wx + e[1]*wy + e[3];
        float c1 = e[4]*wx + e[5]*wy + e[7];
        float c2 = e[8]*wx + e[9]*wy + e[11];
        float pxx = km[0]*c0 + km[1]*c1 + km[2]*c2;
        float pyy = km[3]*c0 + km[4]*c1 + km[5]*c2;
        float pzz = fmaxf(km[6]*c0 + km[7]*c1 + km[8]*c2, 1e-6f);
        float rz = 1.f / pzz;
        float gx = pxx * rz * (2.f / 87.f) - 1.f;
        float gy = pyy * rz * (2.f / 31.f) - 1.f;
        uint4* drow = sampbuf + (size_t)(qg0 + px) * 48 + n * 8;
        #pragma unroll
        for (int p = 0; p < 8; ++p) {
            float sx = fminf(fmaxf(gx + offS[px][2*p],     -1.f), 1.f);
            float sy = fminf(fmaxf(gy + offS[px][2*p + 1], -1.f), 1.f);
            float ixf = fminf((sx + 1.f) * 43.5f, 86.99994f);   // x0 <= 86 -> x1=x0+1 safe
            float iyf = fminf((sy + 1.f) * 15.5f, 30.99998f);   // y0 <= 30
            float x0f = floorf(ixf), y0f = floorf(iyf);
            float fx = ixf - x0f, fy = iyf - y0f;
            float gxw = 1.f - fx, gyw = 1.f - fy;
            uint4 rec;
            rec.x = packrtz(gxw * gyw, fx * gyw);   // {w00, w01}
            rec.y = packrtz(gxw * fy,  fx * fy);    // {w10, w11}
            rec.z = (uint_t)((int)(y0f * 88.f + x0f) * 512);
            rec.w = 0;
            drow[p] = rec;
        }
    }
}

// ---------------------------------------------------------------------------
// Attention: 512 threads = 8 waves = 4 queries x 2 camera-halves.
// Per camera: batch-issue all 32 tap loads into register arrays (ILP),
// then math phase. launch_bounds(512,4) allows ~128 VGPR (2 blocks/CU).
// ---------------------------------------------------------------------------
__global__ __launch_bounds__(512, 4) void attn_kernel(
    const ushort_t* __restrict__ kvb,     // [12][NPIX][256] f16 interleaved
    const ushort_t* __restrict__ qb,      // [qg][128] f16
    const uint4*    __restrict__ sampbuf, // [qg][48]
    float* __restrict__ wbuf)             // [b][128][4096]
{
    __shared__ uint4 recS[192];           // 4 queries x 48 recs
    __shared__ float trS[8][132];
    const int bid = blockIdx.x;
    const int swz = (bid & 7) * 256 + (bid >> 3);   // XCD-chunked, bijective (2048%8==0)
    const int t    = threadIdx.x;
    const int lane = t & 63;
    const int w    = t >> 6;              // 0..7
    const int ql   = w >> 1;              // query within block
    const int c0   = (w & 1) * 3;         // first camera of this half
    const int qg0  = swz * 4;
    const int qg   = qg0 + ql;
    const int b    = qg >> 12;

    if (t < 192) recS[t] = sampbuf[(size_t)qg0 * 48 + t];
    const h2 qh = u2h(((const uint_t*)qb)[(size_t)qg * 64 + lane]);
    __syncthreads();

    float out0 = 0.f, out1 = 0.f;
    #pragma unroll
    for (int i = 0; i < 3; ++i) {
        const int n = c0 + i;
        const char* cb = (const char*)kvb + ((size_t)(b * 6 + n) * NPIX) * 512 + (size_t)lane * 8;
        const uint4* rrow = &recS[ql * 48 + n * 8];

        // ---- phase A: issue all loads (statically indexed -> registers) ----
        uint2 t00[8], t01[8], t10[8], t11[8];
        h2 wAv[8], wBv[8];
        #pragma unroll
        for (int p = 0; p < 8; ++p) {
            uint4 rec = rrow[p];
            wAv[p] = u2h(rec.x);
            wBv[p] = u2h(rec.y);
            const char* r0 = cb + rec.z;
            t00[p] = *(const uint2*)r0;
            t01[p] = *(const uint2*)(r0 + 512);
            t10[p] = *(const uint2*)(r0 + IMW * 512);
            t11[p] = *(const uint2*)(r0 + IMW * 512 + 512);
        }
        // ---- phase B: math ----
        float ssum = 0.f, vac0 = 0.f, vac1 = 0.f;
        #pragma unroll
        for (int p = 0; p < 8; ++p) {
            h2 w00 = {wAv[p].x, wAv[p].x}, w01 = {wAv[p].y, wAv[p].y};
            h2 w10 = {wBv[p].x, wBv[p].x}, w11 = {wBv[p].y, wBv[p].y};
            h2 kb = u2h(t00[p].x)*w00 + u2h(t01[p].x)*w01 + u2h(t10[p].x)*w10 + u2h(t11[p].x)*w11;
            h2 vb = u2h(t00[p].y)*w00 + u2h(t01[p].y)*w01 + u2h(t10[p].y)*w10 + u2h(t11[p].y)*w11;
#if __has_builtin(__builtin_amdgcn_fdot2)
            float s = __builtin_amdgcn_fdot2(qh, kb, 0.f, false);
#else
            float s = (float)qh.x * (float)kb.x + (float)qh.y * (float)kb.y;
#endif
            DPPADD(s, 0xB1);    // quad_perm xor1
            DPPADD(s, 0x4E);    // quad_perm xor2
            DPPADD(s, 0x141);   // row_half_mirror (xor4)
            DPPADD(s, 0x140);   // row_mirror      (xor8)
            float es = __expf(s);
            ssum += es;
            vac0 += es * (float)vb.x;
            vac1 += es * (float)vb.y;
        }
        float inv = 1.f / ssum;
        out0 += vac0 * inv;
        out1 += vac1 * inv;
    }
    *(float2*)&trS[w][2 * lane] = make_float2(out0 * (1.f / NCAM), out1 * (1.f / NCAM));
    __syncthreads();
    if (t < 128) {
        int hw0 = qg0 & 4095;
        float4 v = make_float4(trS[0][t] + trS[1][t], trS[2][t] + trS[3][t],
                               trS[4][t] + trS[5][t], trS[6][t] + trS[7][t]);
        *(float4*)&wbuf[((size_t)(qg0 >> 12) * 128 + t) * 4096 + hw0] = v;
    }
}

// ---------------------------------------------------------------------------
// Generic 64x64 SGEMM (output projection).
// ---------------------------------------------------------------------------
__global__ __launch_bounds__(256) void sgemm_kernel(
    const float* __restrict__ A, const float* __restrict__ B,
    const float* __restrict__ bias, float* __restrict__ C,
    int M, int N, int K, long strideB, long strideC)
{
    __shared__ float As[16][68];
    __shared__ float Bs[16][68];
    const float* Bb = B + (size_t)blockIdx.z * strideB;
    float*       Cb = C + (size_t)blockIdx.z * strideC;
    const int tid = threadIdx.x;
    const int bm = blockIdx.y * 64, bn = blockIdx.x * 64;
    const int tm = ((tid >> 4) & 15) << 2;
    const int tn = (tid & 15) << 2;

    float acc[4][4] = {};
    for (int k0 = 0; k0 < K; k0 += 16) {
        #pragma unroll
        for (int i = 0; i < 4; ++i) {
            int idx = tid + i * 256;
            int mk = idx >> 4, kk = idx & 15;
            As[kk][mk] = A[(size_t)(bm + mk) * K + (k0 + kk)];
        }
        #pragma unroll
        for (int i = 0; i < 4; ++i) {
            int idx = tid + i * 256;
            int kk = idx >> 6, nn = idx & 63;
            Bs[kk][nn] = Bb[(size_t)(k0 + kk) * N + (bn + nn)];
        }
        __syncthreads();
        #pragma unroll
        for (int kk = 0; kk < 16; ++kk) {
            const float4 av = *(const float4*)&As[kk][tm];
            const float4 bv = *(const float4*)&Bs[kk][tn];
            const float a[4]  = {av.x, av.y, av.z, av.w};
            const float bb[4] = {bv.x, bv.y, bv.z, bv.w};
            #pragma unroll
            for (int i = 0; i < 4; ++i)
                #pragma unroll
                for (int j = 0; j < 4; ++j) acc[i][j] += a[i] * bb[j];
        }
        __syncthreads();
    }
    #pragma unroll
    for (int i = 0; i < 4; ++i) {
        int gm = bm + tm + i;
        float bi = bias[gm];
        float4 v = make_float4(acc[i][0]+bi, acc[i][1]+bi, acc[i][2]+bi, acc[i][3]+bi);
        *(float4*)&Cb[(size_t)gm * N + (bn + tn)] = v;
    }
}

// ---------------------------------------------------------------------------
extern "C" void kernel_launch(void* const* d_in, const int* in_sizes, int n_in,
                              void* d_out, int out_size, void* d_ws, size_t ws_size,
                              hipStream_t stream)
{
    const float* bev   = (const float*)d_in[0];
    const float* img   = (const float*)d_in[1];
    const float* Kin   = (const float*)d_in[2];
    const float* Ein   = (const float*)d_in[3];
    const float* wxy   = (const float*)d_in[4];
    const float* wq    = (const float*)d_in[5];
    const float* bq    = (const float*)d_in[6];
    const float* wkv   = (const float*)d_in[7];
    const float* bkv   = (const float*)d_in[8];
    const float* woff1 = (const float*)d_in[9];
    const float* boff1 = (const float*)d_in[10];
    const float* woff2 = (const float*)d_in[11];
    const float* boff2 = (const float*)d_in[12];
    const float* wproj = (const float*)d_in[13];
    const float* bproj = (const float*)d_in[14];
    float* out = (float*)d_out;

    char* wsb = (char*)d_ws;
    ushort_t* kvb   = (ushort_t*)wsb;                       // 17,301,504 B
    ushort_t* imgTb = (ushort_t*)(wsb + 17301504);          //  8,650,752 B
    ushort_t* qbb   = (ushort_t*)(wsb + 25952256);          //  2,097,152 B
    uint4*    sampb = (uint4*)   (wsb + 28049408);          //  6,291,456 B
    float*    wbuf  = (float*)   (wsb + 34340864);          //  4,194,304 B

    imgT_kernel<<<dim3(NPIX/64, 12), 256, 0, stream>>>(img, imgTb);
    bev_mlp<<<dim3(2*HWQ/16), 256, 0, stream>>>(
        bev, wq, bq, woff1, boff1, woff2, boff2, Ein, Kin, wxy, qbb, sampb);
    kv_mfma<<<dim3(NPIX/128, 2, 12), 256, 0, stream>>>(wkv, imgTb, bkv, kvb);
    attn_kernel<<<dim3(2*HWQ/4), 512, 0, stream>>>(kvb, qbb, sampb, wbuf);
    sgemm_kernel<<<dim3(HWQ/64, 2, 2), 256, 0, stream>>>(
        wproj, wbuf, bproj, out, 128, HWQ, 128, (long)128*HWQ, (long)128*HWQ);
}

// Round 8
// 105.309 us; speedup vs baseline: 3.1017x; 1.0341x over previous
//
#include <hip/hip_runtime.h>

#define HWQ  4096      // H*W = 64*64
#define NCAM 6
#define IMH  32
#define IMW  88
#define NPIX (IMH*IMW) // 2816

typedef unsigned short ushort_t;
typedef unsigned int   uint_t;
typedef __fp16 h2   __attribute__((ext_vector_type(2)));
typedef __fp16 f16x8 __attribute__((ext_vector_type(8)));
typedef float  f32x4 __attribute__((ext_vector_type(4)));

union UH { uint_t u; h2 h; };
__device__ inline h2 u2h(uint_t x){ UH c; c.u = x; return c.h; }
__device__ inline uint_t packrtz(float a, float b){
    UH c; c.h = __builtin_amdgcn_cvt_pkrtz(a, b); return c.u;
}

// butterfly add within 16-lane rows, VALU-only (DPP)
#define DPPADD(s, ctrl) { \
    int _x = __builtin_amdgcn_update_dpp(0, __float_as_int(s), ctrl, 0xF, 0xF, true); \
    s += __int_as_float(_x); }

// ---------------------------------------------------------------------------
// KV 1x1 conv via f16 MFMA, img-transpose FUSED into B staging.
// Block = (128 px) x (64 K-ch + 64 V-ch of half y).
// B-tile staged from img f32 [k][px] -> LDS [px][k] f16 (paired u32 writes,
// px-interleaved thread map -> ~2-way banks). Epilogue stages interleaved
// pixel rows in LDS, stores coalesced uint4.
// Row layout (u16): [k2j,k2j+1,v2j,v2j+1] at 4j (j = half-relative pair idx).
// ---------------------------------------------------------------------------
__global__ __launch_bounds__(256) void kv_mfma(
    const float* __restrict__ wkv, const float* __restrict__ img,
    const float* __restrict__ bias, ushort_t* __restrict__ kvb)
{
    __shared__ ushort_t Al[128][40];    // [tile-row][k] f16
    __shared__ ushort_t Bl[128][40];    // [px][k] f16
    __shared__ ushort_t St[128][140];   // [px][region u16]
    const int t = threadIdx.x;
    const int bx = blockIdx.x * 128;    // px0
    const int y  = blockIdx.y;          // ch half
    const int z  = blockIdx.z;
    const int lane = t & 63, wid = t >> 6;
    const int wr = wid >> 1, wc = wid & 1;
    const int srow = t >> 1, spart = t & 1;
    const int grA = (srow < 64) ? (y * 64 + srow) : (64 + y * 64 + srow);
    const int tp  = t >> 4;             // k-pair id (0..15)
    const int pxs = t & 15;             // px phase
    const float* imgz = img + (size_t)z * 128 * NPIX;

    f32x4 zero4 = {0.f, 0.f, 0.f, 0.f};
    f32x4 acc[4][4];
    #pragma unroll
    for (int i = 0; i < 4; ++i)
        #pragma unroll
        for (int j = 0; j < 4; ++j) acc[i][j] = zero4;

    for (int k0 = 0; k0 < 128; k0 += 32) {
        // A: wkv f32 -> f16 LDS
        const float* ap = &wkv[(size_t)grA * 128 + k0 + spart * 16];
        float4 a0 = *(const float4*)(ap+0), a1 = *(const float4*)(ap+4);
        float4 a2 = *(const float4*)(ap+8), a3 = *(const float4*)(ap+12);
        uint4 w0, w1;
        w0.x = packrtz(a0.x,a0.y); w0.y = packrtz(a0.z,a0.w);
        w0.z = packrtz(a1.x,a1.y); w0.w = packrtz(a1.z,a1.w);
        w1.x = packrtz(a2.x,a2.y); w1.y = packrtz(a2.z,a2.w);
        w1.z = packrtz(a3.x,a3.y); w1.w = packrtz(a3.z,a3.w);
        *(uint4*)&Al[srow][spart*16]     = w0;
        *(uint4*)&Al[srow][spart*16 + 8] = w1;
        // B: img f32 -> transposed f16 LDS (rows k0+2tp, k0+2tp+1)
        {
            const float* r0p = imgz + (size_t)(k0 + 2*tp) * NPIX + bx + pxs;
            const float* r1p = r0p + NPIX;
            #pragma unroll
            for (int j = 0; j < 8; ++j) {
                float av = r0p[16*j], cv = r1p[16*j];
                *(uint_t*)&Bl[pxs + 16*j][2*tp] = packrtz(av, cv);
            }
        }
        __syncthreads();
        f16x8 af[4], bf[4];
        #pragma unroll
        for (int mi = 0; mi < 4; ++mi)
            af[mi] = *(const f16x8*)&Al[wr*64 + mi*16 + (lane & 15)][(lane >> 4) * 8];
        #pragma unroll
        for (int ni = 0; ni < 4; ++ni)
            bf[ni] = *(const f16x8*)&Bl[wc*64 + ni*16 + (lane & 15)][(lane >> 4) * 8];
        #pragma unroll
        for (int mi = 0; mi < 4; ++mi)
            #pragma unroll
            for (int ni = 0; ni < 4; ++ni)
                acc[mi][ni] = __builtin_amdgcn_mfma_f32_16x16x32_f16(af[mi], bf[ni], acc[mi][ni], 0, 0, 0);
        __syncthreads();
    }

    // ---- epilogue: LDS stage (interleaved layout), then coalesced store ----
    #pragma unroll
    for (int mi = 0; mi < 4; ++mi) {
        int m0  = wr * 64 + mi * 16 + (lane >> 4) * 4;   // tile row (4 consecutive)
        int gm0 = (m0 < 64) ? (y * 64 + m0) : (64 + y * 64 + m0);
        float4 bsv = *(const float4*)&bias[gm0];
        int off0 = (m0 < 64) ? (2 * m0) : (2 * (m0 - 64) + 2);
        #pragma unroll
        for (int ni = 0; ni < 4; ++ni) {
            int pxl = wc * 64 + ni * 16 + (lane & 15);
            f32x4 d = acc[mi][ni];
            *(uint_t*)&St[pxl][off0]     = packrtz(d.x + bsv.x, d.y + bsv.y);
            *(uint_t*)&St[pxl][off0 + 4] = packrtz(d.z + bsv.z, d.w + bsv.w);
        }
    }
    __syncthreads();
    #pragma unroll
    for (int it = 0; it < 8; ++it) {
        int idx = t + it * 256;              // 0..2047
        int px = idx >> 4, c16 = idx & 15;
        uint4 v = *(const uint4*)&St[px][c16 * 8];
        *(uint4*)&kvb[((size_t)z * NPIX + bx + px) * 256 + y * 128 + c16 * 8] = v;
    }
}

// ---------------------------------------------------------------------------
// Fused BEV-side: q-proj (f16 out), offset MLP, camera projection,
// per-sample bilinear weight/address precompute. 16 px per block.
// ---------------------------------------------------------------------------
__global__ __launch_bounds__(256) void bev_mlp(
    const float* __restrict__ bev,
    const float* __restrict__ wq,    const float* __restrict__ bq,
    const float* __restrict__ woff1, const float* __restrict__ boff1,
    const float* __restrict__ woff2, const float* __restrict__ boff2,
    const float* __restrict__ Ein,   const float* __restrict__ Kin,
    const float* __restrict__ wxy,
    ushort_t* __restrict__ qb, uint4* __restrict__ sampbuf)
{
    __shared__ float bevS[128][20];   // [k][px]
    __shared__ float Ws[32][260];     // [k][out] chunk (q outs 0..127, o1 outs 128..255)
    __shared__ float o1S[128][20];    // [k][px]
    __shared__ float offS[16][16];    // [px][o]
    const int t = threadIdx.x;
    const int qg0 = blockIdx.x * 16;
    const int b   = qg0 >> 12;
    const int hw0 = qg0 & 4095;

    #pragma unroll
    for (int i = 0; i < 2; ++i) {
        int f4 = t + i * 256;                 // 0..511
        int ch = f4 >> 2, part = f4 & 3;
        float4 v = *(const float4*)&bev[((size_t)b * 128 + ch) * 4096 + hw0 + part * 4];
        *(float4*)&bevS[ch][part * 4] = v;
    }
    const float* wrow = (t < 128) ? (wq + (size_t)t * 128) : (woff1 + (size_t)(t - 128) * 128);

    const int og = t >> 2, pxg = t & 3;
    float acc[4][4] = {};
    for (int k0 = 0; k0 < 128; k0 += 32) {
        __syncthreads();
        #pragma unroll
        for (int i = 0; i < 8; ++i) {         // stage W^T chunk
            float4 wv = *(const float4*)&wrow[k0 + i * 4];
            Ws[i*4+0][t] = wv.x; Ws[i*4+1][t] = wv.y;
            Ws[i*4+2][t] = wv.z; Ws[i*4+3][t] = wv.w;
        }
        __syncthreads();
        #pragma unroll
        for (int kk = 0; kk < 32; ++kk) {
            float4 w4 = *(const float4*)&Ws[kk][og * 4];
            float4 b4 = *(const float4*)&bevS[k0 + kk][pxg * 4];
            float wa[4] = {w4.x, w4.y, w4.z, w4.w};
            float ba[4] = {b4.x, b4.y, b4.z, b4.w};
            #pragma unroll
            for (int i = 0; i < 4; ++i)
                #pragma unroll
                for (int j = 0; j < 4; ++j) acc[i][j] += wa[i] * ba[j];
        }
    }
    __syncthreads();
    if (og < 32) {                            // q epilogue -> f16 pixel-major
        int ch = og * 4;
        float4 bqv = *(const float4*)&bq[ch];
        #pragma unroll
        for (int j = 0; j < 4; ++j) {
            int px = pxg * 4 + j;
            uint_t u0 = packrtz(acc[0][j] + bqv.x, acc[1][j] + bqv.y);
            uint_t u1 = packrtz(acc[2][j] + bqv.z, acc[3][j] + bqv.w);
            *(uint2*)&qb[(size_t)(qg0 + px) * 128 + ch] = make_uint2(u0, u1);
        }
    } else {                                  // o1 -> LDS (bias + relu)
        int ch = og * 4 - 128;
        float bov[4] = {boff1[ch], boff1[ch+1], boff1[ch+2], boff1[ch+3]};
        #pragma unroll
        for (int i = 0; i < 4; ++i)
            #pragma unroll
            for (int j = 0; j < 4; ++j)
                o1S[ch + i][pxg * 4 + j] = fmaxf(acc[i][j] + bov[i], 0.f);
    }
    __syncthreads();
    {                                         // off2: thread (o, px)
        int o = t >> 4, px = t & 15;
        const float* w2 = woff2 + (size_t)o * 128;
        float s = boff2[o];
        for (int k = 0; k < 128; k += 4) {
            float4 wv = *(const float4*)&w2[k];
            s += wv.x * o1S[k][px]   + wv.y * o1S[k+1][px]
               + wv.z * o1S[k+2][px] + wv.w * o1S[k+3][px];
        }
        offS[px][o] = s;
    }
    __syncthreads();
    if (t < 96) {                             // sample-prep: (n, px)
        int n = t >> 4, px = t & 15;
        int hw = hw0 + px;
        float wx = wxy[hw], wy = wxy[4096 + hw];
        const float* e  = Ein + (size_t)(b * 6 + n) * 16;
        const float* km = Kin + (size_t)(b * 6 + n) * 9;
        float c0 = e[0]*wx + e[1]*wy + e[3];
        float c1 = e[4]*wx + e[5]*wy + e[7];
        float c2 = e[8]*wx + e[9]*wy + e[11];
        float pxx = km[0]*c0 + km[1]*c1 + km[2]*c2;
        float pyy = km[3]*c0 + km[4]*c1 + km[5]*c2;
        float pzz = fmaxf(km[6]*c0 + km[7]*c1 + km[8]*c2, 1e-6f);
        float rz = 1.f / pzz;
        float gx = pxx * rz * (2.f / 87.f) - 1.f;
        float gy = pyy * rz * (2.f / 31.f) - 1.f;
        uint4* drow = sampbuf + (size_t)(qg0 + px) * 48 + n * 8;
        #pragma unroll
        for (int p = 0; p < 8; ++p) {
            float sx = fminf(fmaxf(gx + offS[px][2*p],     -1.f), 1.f);
            float sy = fminf(fmaxf(gy + offS[px][2*p + 1], -1.f), 1.f);
            float ixf = fminf((sx + 1.f) * 43.5f, 86.99994f);   // x0 <= 86 -> x1=x0+1 safe
            float iyf = fminf((sy + 1.f) * 15.5f, 30.99998f);   // y0 <= 30
            float x0f = floorf(ixf), y0f = floorf(iyf);
            float fx = ixf - x0f, fy = iyf - y0f;
            float gxw = 1.f - fx, gyw = 1.f - fy;
            uint4 rec;
            rec.x = packrtz(gxw * gyw, fx * gyw);   // {w00, w01}
            rec.y = packrtz(gxw * fy,  fx * fy);    // {w10, w11}
            rec.z = (uint_t)((int)(y0f * 88.f + x0f) * 512);
            rec.w = 0;
            drow[p] = rec;
        }
    }
}

// ---------------------------------------------------------------------------
// Attention: 512 threads = 8 waves = 4 queries x 2 camera-halves.
// Queries mapped via Morton tiles: XCD chunk (256 blocks) = 32x32 BEV patch
// -> compact per-XCD image working set for L2 residency.
// Output pixel-major [qg][128] (coalesced); proj GEMM does B^T read.
// ---------------------------------------------------------------------------
__global__ __launch_bounds__(512, 4) void attn_kernel(
    const ushort_t* __restrict__ kvb,     // [12][NPIX][256] f16 interleaved
    const ushort_t* __restrict__ qb,      // [qg][128] f16
    const uint4*    __restrict__ sampbuf, // [qg][48]
    float* __restrict__ wbuf)             // [qg][128] pixel-major
{
    __shared__ uint4 recS[192];           // 4 queries x 48 recs
    __shared__ float trS[8][132];
    const int bid = blockIdx.x;
    const int swz = (bid & 7) * 256 + (bid >> 3);   // XCD-chunked, bijective
    const int t    = threadIdx.x;
    const int lane = t & 63;
    const int w    = t >> 6;              // 0..7
    const int ql   = w >> 1;              // query within block (0..3)
    const int c0   = (w & 1) * 3;         // first camera of this half
    const int b    = swz >> 10;
    const int tix  = swz & 1023;
    // Morton decode: tx = even bits, ty = odd bits (5 each)
    const int tx = (tix&1) | ((tix>>1)&2) | ((tix>>2)&4) | ((tix>>3)&8) | ((tix>>4)&16);
    const int ty = ((tix>>1)&1) | ((tix>>2)&2) | ((tix>>3)&4) | ((tix>>4)&8) | ((tix>>5)&16);

    // qg of query slot q (0..3): 2x2 patch at (2tx, 2ty)
    #define QG_OF(q) (b * 4096 + (ty*2 + ((q)>>1)) * 64 + tx*2 + ((q)&1))

    if (t < 192) {
        int q2 = t / 48, r = t - q2 * 48;
        recS[t] = sampbuf[(size_t)QG_OF(q2) * 48 + r];
    }
    const int qg = QG_OF(ql);
    const h2 qh = u2h(((const uint_t*)qb)[(size_t)qg * 64 + lane]);
    __syncthreads();

    float out0 = 0.f, out1 = 0.f;
    #pragma unroll
    for (int i = 0; i < 3; ++i) {
        const int n = c0 + i;
        const char* cb = (const char*)kvb + ((size_t)(b * 6 + n) * NPIX) * 512 + (size_t)lane * 8;
        const uint4* rrow = &recS[ql * 48 + n * 8];
        float ssum = 0.f, vac0 = 0.f, vac1 = 0.f;
        #pragma unroll
        for (int p = 0; p < 8; ++p) {
            uint4 rec = rrow[p];
            h2 wA = u2h(rec.x), wB = u2h(rec.y);
            const char* r0 = cb + rec.z;
            uint2 a00 = *(const uint2*)r0;
            uint2 a01 = *(const uint2*)(r0 + 512);
            uint2 a10 = *(const uint2*)(r0 + IMW * 512);
            uint2 a11 = *(const uint2*)(r0 + IMW * 512 + 512);
            h2 w00 = {wA.x, wA.x}, w01 = {wA.y, wA.y};
            h2 w10 = {wB.x, wB.x}, w11 = {wB.y, wB.y};
            h2 kb = u2h(a00.x)*w00 + u2h(a01.x)*w01 + u2h(a10.x)*w10 + u2h(a11.x)*w11;
            h2 vb = u2h(a00.y)*w00 + u2h(a01.y)*w01 + u2h(a10.y)*w10 + u2h(a11.y)*w11;
#if __has_builtin(__builtin_amdgcn_fdot2)
            float s = __builtin_amdgcn_fdot2(qh, kb, 0.f, false);
#else
            float s = (float)qh.x * (float)kb.x + (float)qh.y * (float)kb.y;
#endif
            DPPADD(s, 0xB1);    // quad_perm xor1
            DPPADD(s, 0x4E);    // quad_perm xor2
            DPPADD(s, 0x141);   // row_half_mirror (xor4)
            DPPADD(s, 0x140);   // row_mirror      (xor8)
            float es = __expf(s);
            ssum += es;
            vac0 += es * (float)vb.x;
            vac1 += es * (float)vb.y;
        }
        float inv = 1.f / ssum;
        out0 += vac0 * inv;
        out1 += vac1 * inv;
    }
    *(float2*)&trS[w][2 * lane] = make_float2(out0 * (1.f / NCAM), out1 * (1.f / NCAM));
    __syncthreads();
    {
        int qs = t >> 7, ch = t & 127;
        wbuf[(size_t)QG_OF(qs) * 128 + ch] = trS[2*qs][ch] + trS[2*qs+1][ch];
    }
    #undef QG_OF
}

// ---------------------------------------------------------------------------
// Output projection: C[b][128][4096] = wproj @ wbuf^T  (B pixel-major [qg][128])
// ---------------------------------------------------------------------------
__global__ __launch_bounds__(256) void sgemm_kernel(
    const float* __restrict__ A, const float* __restrict__ B,
    const float* __restrict__ bias, float* __restrict__ C)
{
    __shared__ float As[16][68];
    __shared__ float Bs[16][68];
    const int z = blockIdx.z;
    const float* Bb = B + (size_t)z * 4096 * 128;
    float*       Cb = C + (size_t)z * 128 * 4096;
    const int tid = threadIdx.x;
    const int bm = blockIdx.y * 64, bn = blockIdx.x * 64;
    const int tm = ((tid >> 4) & 15) << 2;
    const int tn = (tid & 15) << 2;

    float acc[4][4] = {};
    for (int k0 = 0; k0 < 128; k0 += 16) {
        #pragma unroll
        for (int i = 0; i < 4; ++i) {
            int idx = tid + i * 256;
            int mk = idx >> 4, kk = idx & 15;
            As[kk][mk] = A[(size_t)(bm + mk) * 128 + (k0 + kk)];
        }
        {   // B^T: wbuf [px][128]
            int pxl = tid >> 2, kc = (tid & 3) * 4;
            float4 bv = *(const float4*)&Bb[(size_t)(bn + pxl) * 128 + k0 + kc];
            Bs[kc+0][pxl] = bv.x; Bs[kc+1][pxl] = bv.y;
            Bs[kc+2][pxl] = bv.z; Bs[kc+3][pxl] = bv.w;
        }
        __syncthreads();
        #pragma unroll
        for (int kk = 0; kk < 16; ++kk) {
            const float4 av = *(const float4*)&As[kk][tm];
            const float4 bv = *(const float4*)&Bs[kk][tn];
            const float a[4]  = {av.x, av.y, av.z, av.w};
            const float bb[4] = {bv.x, bv.y, bv.z, bv.w};
            #pragma unroll
            for (int i = 0; i < 4; ++i)
                #pragma unroll
                for (int j = 0; j < 4; ++j) acc[i][j] += a[i] * bb[j];
        }
        __syncthreads();
    }
    #pragma unroll
    for (int i = 0; i < 4; ++i) {
        int gm = bm + tm + i;
        float bi = bias[gm];
        float4 v = make_float4(acc[i][0]+bi, acc[i][1]+bi, acc[i][2]+bi, acc[i][3]+bi);
        *(float4*)&Cb[(size_t)gm * 4096 + (bn + tn)] = v;
    }
}

// ---------------------------------------------------------------------------
extern "C" void kernel_launch(void* const* d_in, const int* in_sizes, int n_in,
                              void* d_out, int out_size, void* d_ws, size_t ws_size,
                              hipStream_t stream)
{
    const float* bev   = (const float*)d_in[0];
    const float* img   = (const float*)d_in[1];
    const float* Kin   = (const float*)d_in[2];
    const float* Ein   = (const float*)d_in[3];
    const float* wxy   = (const float*)d_in[4];
    const float* wq    = (const float*)d_in[5];
    const float* bq    = (const float*)d_in[6];
    const float* wkv   = (const float*)d_in[7];
    const float* bkv   = (const float*)d_in[8];
    const float* woff1 = (const float*)d_in[9];
    const float* boff1 = (const float*)d_in[10];
    const float* woff2 = (const float*)d_in[11];
    const float* boff2 = (const float*)d_in[12];
    const float* wproj = (const float*)d_in[13];
    const float* bproj = (const float*)d_in[14];
    float* out = (float*)d_out;

    char* wsb = (char*)d_ws;
    ushort_t* kvb   = (ushort_t*)wsb;                       // 17,301,504 B
    ushort_t* qbb   = (ushort_t*)(wsb + 17301504);          //  2,097,152 B
    uint4*    sampb = (uint4*)   (wsb + 19398656);          //  6,291,456 B
    float*    wbuf  = (float*)   (wsb + 25690112);          //  4,194,304 B

    bev_mlp<<<dim3(2*HWQ/16), 256, 0, stream>>>(
        bev, wq, bq, woff1, boff1, woff2, boff2, Ein, Kin, wxy, qbb, sampb);
    kv_mfma<<<dim3(NPIX/128, 2, 12), 256, 0, stream>>>(wkv, img, bkv, kvb);
    attn_kernel<<<dim3(2*HWQ/4), 512, 0, stream>>>(kvb, qbb, sampb, wbuf);
    sgemm_kernel<<<dim3(HWQ/64, 2, 2), 256, 0, stream>>>(wproj, wbuf, bproj, out);
}

// Round 9
// 85.170 us; speedup vs baseline: 3.8352x; 1.2365x over previous
//
#include <hip/hip_runtime.h>

#define HWQ  4096      // H*W = 64*64
#define NCAM 6
#define IMH  32
#define IMW  88
#define NPIX (IMH*IMW) // 2816

typedef unsigned short ushort_t;
typedef unsigned int   uint_t;
typedef __fp16 h2   __attribute__((ext_vector_type(2)));
typedef __fp16 f16x8 __attribute__((ext_vector_type(8)));
typedef float  f32x4 __attribute__((ext_vector_type(4)));

union UH { uint_t u; h2 h; };
__device__ inline h2 u2h(uint_t x){ UH c; c.u = x; return c.h; }
__device__ inline uint_t packrtz(float a, float b){
    UH c; c.h = __builtin_amdgcn_cvt_pkrtz(a, b); return c.u;
}

// butterfly add, VALU-only (DPP)
#define DPPADD(s, ctrl) { \
    int _x = __builtin_amdgcn_update_dpp(0, __float_as_int(s), ctrl, 0xF, 0xF, true); \
    s += __int_as_float(_x); }

// ---------------------------------------------------------------------------
// KV 1x1 conv via f16 MFMA, img-transpose fused into B staging.
// Row layout (u16[256] per pixel): [k2t,k2t+1,v2t,v2t+1] at 4t.
// ---------------------------------------------------------------------------
__global__ __launch_bounds__(256) void kv_mfma(
    const float* __restrict__ wkv, const float* __restrict__ img,
    const float* __restrict__ bias, ushort_t* __restrict__ kvb)
{
    __shared__ ushort_t Al[128][40];    // [tile-row][k] f16
    __shared__ ushort_t Bl[128][40];    // [px][k] f16
    __shared__ ushort_t St[128][140];   // [px][region u16]
    const int t = threadIdx.x;
    const int bx = blockIdx.x * 128;    // px0
    const int y  = blockIdx.y;          // ch half
    const int z  = blockIdx.z;
    const int lane = t & 63, wid = t >> 6;
    const int wr = wid >> 1, wc = wid & 1;
    const int srow = t >> 1, spart = t & 1;
    const int grA = (srow < 64) ? (y * 64 + srow) : (64 + y * 64 + srow);
    const int tp  = t >> 4;             // k-pair id (0..15)
    const int pxs = t & 15;             // px phase
    const float* imgz = img + (size_t)z * 128 * NPIX;

    f32x4 zero4 = {0.f, 0.f, 0.f, 0.f};
    f32x4 acc[4][4];
    #pragma unroll
    for (int i = 0; i < 4; ++i)
        #pragma unroll
        for (int j = 0; j < 4; ++j) acc[i][j] = zero4;

    for (int k0 = 0; k0 < 128; k0 += 32) {
        const float* ap = &wkv[(size_t)grA * 128 + k0 + spart * 16];
        float4 a0 = *(const float4*)(ap+0), a1 = *(const float4*)(ap+4);
        float4 a2 = *(const float4*)(ap+8), a3 = *(const float4*)(ap+12);
        uint4 w0, w1;
        w0.x = packrtz(a0.x,a0.y); w0.y = packrtz(a0.z,a0.w);
        w0.z = packrtz(a1.x,a1.y); w0.w = packrtz(a1.z,a1.w);
        w1.x = packrtz(a2.x,a2.y); w1.y = packrtz(a2.z,a2.w);
        w1.z = packrtz(a3.x,a3.y); w1.w = packrtz(a3.z,a3.w);
        *(uint4*)&Al[srow][spart*16]     = w0;
        *(uint4*)&Al[srow][spart*16 + 8] = w1;
        {
            const float* r0p = imgz + (size_t)(k0 + 2*tp) * NPIX + bx + pxs;
            const float* r1p = r0p + NPIX;
            #pragma unroll
            for (int j = 0; j < 8; ++j) {
                float av = r0p[16*j], cv = r1p[16*j];
                *(uint_t*)&Bl[pxs + 16*j][2*tp] = packrtz(av, cv);
            }
        }
        __syncthreads();
        f16x8 af[4], bf[4];
        #pragma unroll
        for (int mi = 0; mi < 4; ++mi)
            af[mi] = *(const f16x8*)&Al[wr*64 + mi*16 + (lane & 15)][(lane >> 4) * 8];
        #pragma unroll
        for (int ni = 0; ni < 4; ++ni)
            bf[ni] = *(const f16x8*)&Bl[wc*64 + ni*16 + (lane & 15)][(lane >> 4) * 8];
        #pragma unroll
        for (int mi = 0; mi < 4; ++mi)
            #pragma unroll
            for (int ni = 0; ni < 4; ++ni)
                acc[mi][ni] = __builtin_amdgcn_mfma_f32_16x16x32_f16(af[mi], bf[ni], acc[mi][ni], 0, 0, 0);
        __syncthreads();
    }

    #pragma unroll
    for (int mi = 0; mi < 4; ++mi) {
        int m0  = wr * 64 + mi * 16 + (lane >> 4) * 4;
        int gm0 = (m0 < 64) ? (y * 64 + m0) : (64 + y * 64 + m0);
        float4 bsv = *(const float4*)&bias[gm0];
        int off0 = (m0 < 64) ? (2 * m0) : (2 * (m0 - 64) + 2);
        #pragma unroll
        for (int ni = 0; ni < 4; ++ni) {
            int pxl = wc * 64 + ni * 16 + (lane & 15);
            f32x4 d = acc[mi][ni];
            *(uint_t*)&St[pxl][off0]     = packrtz(d.x + bsv.x, d.y + bsv.y);
            *(uint_t*)&St[pxl][off0 + 4] = packrtz(d.z + bsv.z, d.w + bsv.w);
        }
    }
    __syncthreads();
    #pragma unroll
    for (int it = 0; it < 8; ++it) {
        int idx = t + it * 256;
        int px = idx >> 4, c16 = idx & 15;
        uint4 v = *(const uint4*)&St[px][c16 * 8];
        *(uint4*)&kvb[((size_t)z * NPIX + bx + px) * 256 + y * 128 + c16 * 8] = v;
    }
}

// ---------------------------------------------------------------------------
// Fused BEV-side: q-proj (f16), offset MLP, camera projection, sample records.
// ---------------------------------------------------------------------------
__global__ __launch_bounds__(256) void bev_mlp(
    const float* __restrict__ bev,
    const float* __restrict__ wq,    const float* __restrict__ bq,
    const float* __restrict__ woff1, const float* __restrict__ boff1,
    const float* __restrict__ woff2, const float* __restrict__ boff2,
    const float* __restrict__ Ein,   const float* __restrict__ Kin,
    const float* __restrict__ wxy,
    ushort_t* __restrict__ qb, uint4* __restrict__ sampbuf)
{
    __shared__ float bevS[128][20];
    __shared__ float Ws[32][260];
    __shared__ float o1S[128][20];
    __shared__ float offS[16][16];
    const int t = threadIdx.x;
    const int qg0 = blockIdx.x * 16;
    const int b   = qg0 >> 12;
    const int hw0 = qg0 & 4095;

    #pragma unroll
    for (int i = 0; i < 2; ++i) {
        int f4 = t + i * 256;
        int ch = f4 >> 2, part = f4 & 3;
        float4 v = *(const float4*)&bev[((size_t)b * 128 + ch) * 4096 + hw0 + part * 4];
        *(float4*)&bevS[ch][part * 4] = v;
    }
    const float* wrow = (t < 128) ? (wq + (size_t)t * 128) : (woff1 + (size_t)(t - 128) * 128);

    const int og = t >> 2, pxg = t & 3;
    float acc[4][4] = {};
    for (int k0 = 0; k0 < 128; k0 += 32) {
        __syncthreads();
        #pragma unroll
        for (int i = 0; i < 8; ++i) {
            float4 wv = *(const float4*)&wrow[k0 + i * 4];
            Ws[i*4+0][t] = wv.x; Ws[i*4+1][t] = wv.y;
            Ws[i*4+2][t] = wv.z; Ws[i*4+3][t] = wv.w;
        }
        __syncthreads();
        #pragma unroll
        for (int kk = 0; kk < 32; ++kk) {
            float4 w4 = *(const float4*)&Ws[kk][og * 4];
            float4 b4 = *(const float4*)&bevS[k0 + kk][pxg * 4];
            float wa[4] = {w4.x, w4.y, w4.z, w4.w};
            float ba[4] = {b4.x, b4.y, b4.z, b4.w};
            #pragma unroll
            for (int i = 0; i < 4; ++i)
                #pragma unroll
                for (int j = 0; j < 4; ++j) acc[i][j] += wa[i] * ba[j];
        }
    }
    __syncthreads();
    if (og < 32) {
        int ch = og * 4;
        float4 bqv = *(const float4*)&bq[ch];
        #pragma unroll
        for (int j = 0; j < 4; ++j) {
            int px = pxg * 4 + j;
            uint_t u0 = packrtz(acc[0][j] + bqv.x, acc[1][j] + bqv.y);
            uint_t u1 = packrtz(acc[2][j] + bqv.z, acc[3][j] + bqv.w);
            *(uint2*)&qb[(size_t)(qg0 + px) * 128 + ch] = make_uint2(u0, u1);
        }
    } else {
        int ch = og * 4 - 128;
        float bov[4] = {boff1[ch], boff1[ch+1], boff1[ch+2], boff1[ch+3]};
        #pragma unroll
        for (int i = 0; i < 4; ++i)
            #pragma unroll
            for (int j = 0; j < 4; ++j)
                o1S[ch + i][pxg * 4 + j] = fmaxf(acc[i][j] + bov[i], 0.f);
    }
    __syncthreads();
    {
        int o = t >> 4, px = t & 15;
        const float* w2 = woff2 + (size_t)o * 128;
        float s = boff2[o];
        for (int k = 0; k < 128; k += 4) {
            float4 wv = *(const float4*)&w2[k];
            s += wv.x * o1S[k][px]   + wv.y * o1S[k+1][px]
               + wv.z * o1S[k+2][px] + wv.w * o1S[k+3][px];
        }
        offS[px][o] = s;
    }
    __syncthreads();
    if (t < 96) {
        int n = t >> 4, px = t & 15;
        int hw = hw0 + px;
        float wx = wxy[hw], wy = wxy[4096 + hw];
        const float* e  = Ein + (size_t)(b * 6 + n) * 16;
        const float* km = Kin + (size_t)(b * 6 + n) * 9;
        float c0 = e[0]*wx + e[1]*wy + e[3];
        float c1 = e[4]*wx + e[5]*wy + e[7];
        float c2 = e[8]*wx + e[9]*wy + e[11];
        float pxx = km[0]*c0 + km[1]*c1 + km[2]*c2;
        float pyy = km[3]*c0 + km[4]*c1 + km[5]*c2;
        float pzz = fmaxf(km[6]*c0 + km[7]*c1 + km[8]*c2, 1e-6f);
        float rz = 1.f / pzz;
        float gx = pxx * rz * (2.f / 87.f) - 1.f;
        float gy = pyy * rz * (2.f / 31.f) - 1.f;
        uint4* drow = sampbuf + (size_t)(qg0 + px) * 48 + n * 8;
        #pragma unroll
        for (int p = 0; p < 8; ++p) {
            float sx = fminf(fmaxf(gx + offS[px][2*p],     -1.f), 1.f);
            float sy = fminf(fmaxf(gy + offS[px][2*p + 1], -1.f), 1.f);
            float ixf = fminf((sx + 1.f) * 43.5f, 86.99994f);   // x0 <= 86
            float iyf = fminf((sy + 1.f) * 15.5f, 30.99998f);   // y0 <= 30
            float x0f = floorf(ixf), y0f = floorf(iyf);
            float fx = ixf - x0f, fy = iyf - y0f;
            float gxw = 1.f - fx, gyw = 1.f - fy;
            uint4 rec;
            rec.x = packrtz(gxw * gyw, fx * gyw);   // {w00, w01}
            rec.y = packrtz(gxw * fy,  fx * fy);    // {w10, w11}
            rec.z = (uint_t)((int)(y0f * 88.f + x0f) * 512);
            rec.w = 0;
            drow[p] = rec;
        }
    }
}

// ---------------------------------------------------------------------------
// Attention, camera-affinity version. Grid = 1536 blocks x 512 thr.
// XCD x (= bid%8) gets tasks {3x..3x+2}; task = (slice, query-half) ->
// each XCD touches <=2 camera slices (2.9 MB) -> L2-resident.
// Block = 1 slice x 32 queries; wave = 4 queries; lane = 16*qi + c,
// lane owns channels 8c..8c+7 (one head-quarter). Softmax reduce = 2 DPP.
// Output: per-slice partial, f16, wbuf2[slice][q][128].
// ---------------------------------------------------------------------------
__global__ __launch_bounds__(512, 4) void attn_kernel(
    const ushort_t* __restrict__ kvb,     // [12][NPIX][256] f16 interleaved
    const ushort_t* __restrict__ qb,      // [qg][128] f16
    const uint4*    __restrict__ sampbuf, // [qg][48]
    ushort_t* __restrict__ wbuf2)         // [12][4096][128] f16 partials
{
    __shared__ uint4 recS[256];           // 32 queries x 8 recs (this camera)
    const int bid = blockIdx.x;
    const int x   = bid & 7;
    const int k   = bid >> 3;             // 0..191
    const int task = x * 3 + (k >> 6);    // 0..23
    const int s    = task >> 1;           // slice 0..11
    const int b    = (s >= 6) ? 1 : 0;
    const int n    = s - b * 6;
    const int ql0  = (task & 1) * 2048 + (k & 63) * 32;   // query base in batch

    const int t    = threadIdx.x;
    const int lane = t & 63;
    const int w    = t >> 6;              // wave 0..7
    const int qi   = lane >> 4;           // query in wave
    const int c    = lane & 15;           // channel chunk (8 ch)
    const int q_l  = w * 4 + qi;          // query in block (0..31)
    const int qg   = b * 4096 + ql0 + q_l;

    if (t < 256)
        recS[t] = sampbuf[(size_t)(b * 4096 + ql0 + (t >> 3)) * 48 + n * 8 + (t & 7)];

    const uint4 Q = *(const uint4*)&qb[(size_t)qg * 128 + c * 8];
    const h2 q01 = u2h(Q.x), q23 = u2h(Q.y), q45 = u2h(Q.z), q67 = u2h(Q.w);
    __syncthreads();

    const char* cb = (const char*)kvb + (size_t)s * NPIX * 512 + c * 32;

    float ssum = 0.f;
    float vac0 = 0.f, vac1 = 0.f, vac2 = 0.f, vac3 = 0.f;
    float vac4 = 0.f, vac5 = 0.f, vac6 = 0.f, vac7 = 0.f;

    #pragma unroll 2
    for (int p = 0; p < 8; ++p) {
        uint4 rec = recS[q_l * 8 + p];
        h2 wA = u2h(rec.x), wB = u2h(rec.y);
        h2 w00 = {wA.x, wA.x}, w01 = {wA.y, wA.y};
        h2 w10 = {wB.x, wB.x}, w11 = {wB.y, wB.y};
        const char* r = cb + rec.z;
        uint4 t00a = *(const uint4*)(r);
        uint4 t00b = *(const uint4*)(r + 16);
        uint4 t01a = *(const uint4*)(r + 512);
        uint4 t01b = *(const uint4*)(r + 528);
        uint4 t10a = *(const uint4*)(r + 45056);
        uint4 t10b = *(const uint4*)(r + 45072);
        uint4 t11a = *(const uint4*)(r + 45568);
        uint4 t11b = *(const uint4*)(r + 45584);

        h2 kb01 = u2h(t00a.x)*w00 + u2h(t01a.x)*w01 + u2h(t10a.x)*w10 + u2h(t11a.x)*w11;
        h2 kb23 = u2h(t00a.z)*w00 + u2h(t01a.z)*w01 + u2h(t10a.z)*w10 + u2h(t11a.z)*w11;
        h2 kb45 = u2h(t00b.x)*w00 + u2h(t01b.x)*w01 + u2h(t10b.x)*w10 + u2h(t11b.x)*w11;
        h2 kb67 = u2h(t00b.z)*w00 + u2h(t01b.z)*w01 + u2h(t10b.z)*w10 + u2h(t11b.z)*w11;
        h2 vb01 = u2h(t00a.y)*w00 + u2h(t01a.y)*w01 + u2h(t10a.y)*w10 + u2h(t11a.y)*w11;
        h2 vb23 = u2h(t00a.w)*w00 + u2h(t01a.w)*w01 + u2h(t10a.w)*w10 + u2h(t11a.w)*w11;
        h2 vb45 = u2h(t00b.y)*w00 + u2h(t01b.y)*w01 + u2h(t10b.y)*w10 + u2h(t11b.y)*w11;
        h2 vb67 = u2h(t00b.w)*w00 + u2h(t01b.w)*w01 + u2h(t10b.w)*w10 + u2h(t11b.w)*w11;

#if __has_builtin(__builtin_amdgcn_fdot2)
        float sd = __builtin_amdgcn_fdot2(q01, kb01,
                    __builtin_amdgcn_fdot2(q23, kb23,
                     __builtin_amdgcn_fdot2(q45, kb45,
                      __builtin_amdgcn_fdot2(q67, kb67, 0.f, false), false), false), false);
#else
        float sd = (float)q01.x*(float)kb01.x + (float)q01.y*(float)kb01.y
                 + (float)q23.x*(float)kb23.x + (float)q23.y*(float)kb23.y
                 + (float)q45.x*(float)kb45.x + (float)q45.y*(float)kb45.y
                 + (float)q67.x*(float)kb67.x + (float)q67.y*(float)kb67.y;
#endif
        DPPADD(sd, 0xB1);   // quad xor1
        DPPADD(sd, 0x4E);   // quad xor2  -> sum over the head's 4 lanes
        float es = __expf(sd);
        ssum += es;
        vac0 += es * (float)vb01.x; vac1 += es * (float)vb01.y;
        vac2 += es * (float)vb23.x; vac3 += es * (float)vb23.y;
        vac4 += es * (float)vb45.x; vac5 += es * (float)vb45.y;
        vac6 += es * (float)vb67.x; vac7 += es * (float)vb67.y;
    }
    const float inv = 1.f / (ssum * (float)NCAM);
    uint4 o;
    o.x = packrtz(vac0 * inv, vac1 * inv);
    o.y = packrtz(vac2 * inv, vac3 * inv);
    o.z = packrtz(vac4 * inv, vac5 * inv);
    o.w = packrtz(vac6 * inv, vac7 * inv);
    *(uint4*)&wbuf2[((size_t)s * 4096 + ql0 + q_l) * 128 + c * 8] = o;
}

// ---------------------------------------------------------------------------
// Output projection with 6-camera partial sum in the B^T stage.
// C[b][128][4096] = wproj @ (sum_n wbuf2[b*6+n])^T
// ---------------------------------------------------------------------------
__global__ __launch_bounds__(256) void sgemm_kernel(
    const float* __restrict__ A, const ushort_t* __restrict__ B2,
    const float* __restrict__ bias, float* __restrict__ C)
{
    __shared__ float As[16][68];
    __shared__ float Bs[16][68];
    const int z = blockIdx.z;
    float* Cb = C + (size_t)z * 128 * 4096;
    const int tid = threadIdx.x;
    const int bm = blockIdx.y * 64, bn = blockIdx.x * 64;
    const int tm = ((tid >> 4) & 15) << 2;
    const int tn = (tid & 15) << 2;

    float acc[4][4] = {};
    for (int k0 = 0; k0 < 128; k0 += 16) {
        #pragma unroll
        for (int i = 0; i < 4; ++i) {
            int idx = tid + i * 256;
            int mk = idx >> 4, kk = idx & 15;
            As[kk][mk] = A[(size_t)(bm + mk) * 128 + (k0 + kk)];
        }
        {   // B^T with 6-way partial sum: wbuf2[z*6+n][px][128] f16
            int pxl = tid >> 2, kc = (tid & 3) * 4;
            float b0 = 0.f, b1 = 0.f, b2 = 0.f, b3 = 0.f;
            #pragma unroll
            for (int nn = 0; nn < 6; ++nn) {
                const ushort_t* src = B2 + (((size_t)(z*6+nn) * 4096 + bn + pxl) * 128 + k0 + kc);
                uint2 v = *(const uint2*)src;
                h2 h0 = u2h(v.x), h1 = u2h(v.y);
                b0 += (float)h0.x; b1 += (float)h0.y;
                b2 += (float)h1.x; b3 += (float)h1.y;
            }
            Bs[kc+0][pxl] = b0; Bs[kc+1][pxl] = b1;
            Bs[kc+2][pxl] = b2; Bs[kc+3][pxl] = b3;
        }
        __syncthreads();
        #pragma unroll
        for (int kk = 0; kk < 16; ++kk) {
            const float4 av = *(const float4*)&As[kk][tm];
            const float4 bv = *(const float4*)&Bs[kk][tn];
            const float a[4]  = {av.x, av.y, av.z, av.w};
            const float bb[4] = {bv.x, bv.y, bv.z, bv.w};
            #pragma unroll
            for (int i = 0; i < 4; ++i)
                #pragma unroll
                for (int j = 0; j < 4; ++j) acc[i][j] += a[i] * bb[j];
        }
        __syncthreads();
    }
    #pragma unroll
    for (int i = 0; i < 4; ++i) {
        int gm = bm + tm + i;
        float bi = bias[gm];
        float4 v = make_float4(acc[i][0]+bi, acc[i][1]+bi, acc[i][2]+bi, acc[i][3]+bi);
        *(float4*)&Cb[(size_t)gm * 4096 + (bn + tn)] = v;
    }
}

// ---------------------------------------------------------------------------
extern "C" void kernel_launch(void* const* d_in, const int* in_sizes, int n_in,
                              void* d_out, int out_size, void* d_ws, size_t ws_size,
                              hipStream_t stream)
{
    const float* bev   = (const float*)d_in[0];
    const float* img   = (const float*)d_in[1];
    const float* Kin   = (const float*)d_in[2];
    const float* Ein   = (const float*)d_in[3];
    const float* wxy   = (const float*)d_in[4];
    const float* wq    = (const float*)d_in[5];
    const float* bq    = (const float*)d_in[6];
    const float* wkv   = (const float*)d_in[7];
    const float* bkv   = (const float*)d_in[8];
    const float* woff1 = (const float*)d_in[9];
    const float* boff1 = (const float*)d_in[10];
    const float* woff2 = (const float*)d_in[11];
    const float* boff2 = (const float*)d_in[12];
    const float* wproj = (const float*)d_in[13];
    const float* bproj = (const float*)d_in[14];
    float* out = (float*)d_out;

    char* wsb = (char*)d_ws;
    ushort_t* kvb   = (ushort_t*)wsb;                       // 17,301,504 B
    ushort_t* qbb   = (ushort_t*)(wsb + 17301504);          //  2,097,152 B
    uint4*    sampb = (uint4*)   (wsb + 19398656);          //  6,291,456 B
    ushort_t* wbuf2 = (ushort_t*)(wsb + 25690112);          // 12,582,912 B

    bev_mlp<<<dim3(2*HWQ/16), 256, 0, stream>>>(
        bev, wq, bq, woff1, boff1, woff2, boff2, Ein, Kin, wxy, qbb, sampb);
    kv_mfma<<<dim3(NPIX/128, 2, 12), 256, 0, stream>>>(wkv, img, bkv, kvb);
    attn_kernel<<<dim3(1536), 512, 0, stream>>>(kvb, qbb, sampb, wbuf2);
    sgemm_kernel<<<dim3(HWQ/64, 2, 2), 256, 0, stream>>>(wproj, wbuf2, bproj, out);
}